// Round 6
// baseline (443.200 us; speedup 1.0000x reference)
//
#include <hip/hip_runtime.h>
#include <math.h>

// ---------------------------------------------------------------------------
// Problem constants
// ---------------------------------------------------------------------------
namespace {
constexpr int cB  = 64;
constexpr int cNQ = 32;
constexpr int cND = 512;
constexpr int cNd = cB * cND;   // 32768
constexpr int cNq = cB * cNQ;   // 2048
constexpr int cEd = cNd * 8;    // 262144
constexpr int cEq = cNq * 8;    // 16384
constexpr size_t cSZ = (size_t)cB * cNQ * cND;  // 1M
// mega-kernel block ranges
constexpr int NB_CVT = 2188, NB_T2BF = 808, NB_CNT = (cEd + cEq) / 256;  // 1088
constexpr int NB_FILL = (cEd + cEq) / 256;       // 1088
constexpr int NB_GEMM = (cNd + cNq) / 64;        // 544
constexpr int NB_GATH = (cNd + cNq) / 8;         // 4352
constexpr int NB_PREP = 1792;
constexpr int NB_LEVEL = 1024;
constexpr int NB_COMB = 2048;
}

#define F4C(p) (*(const float4*)(p))
#define F4W(p) (*(float4*)(p))

typedef __attribute__((ext_vector_type(8))) __bf16 bf16x8;
typedef __attribute__((ext_vector_type(4))) float floatx4;

__device__ __forceinline__ ushort f2bf(float f) {
  union { float f; unsigned u; } v;
  v.f = f;
  unsigned u = v.u;
  return (ushort)((u + 0x7fffu + ((u >> 16) & 1u)) >> 16);
}
__device__ __forceinline__ float bf2f(ushort u) {
  union { unsigned u; float f; } v;
  v.u = ((unsigned)u) << 16;
  return v.f;
}
__device__ __forceinline__ float4 us4f4(ushort4 u) {
  return make_float4(bf2f(u.x), bf2f(u.y), bf2f(u.z), bf2f(u.w));
}
__device__ __forceinline__ ushort4 f4us4(float4 f) {
  ushort4 o;
  o.x = f2bf(f.x); o.y = f2bf(f.y); o.z = f2bf(f.z); o.w = f2bf(f.w);
  return o;
}
__device__ __forceinline__ float fexp2(float x) {
#if __has_builtin(__builtin_amdgcn_exp2f)
  return __builtin_amdgcn_exp2f(x);
#else
  return exp2f(x);
#endif
}
__device__ __forceinline__ float frcp(float x) {
#if __has_builtin(__builtin_amdgcn_rcpf)
  return __builtin_amdgcn_rcpf(x);
#else
  return 1.0f / x;
#endif
}
__device__ __forceinline__ float fsigmoid(float z) {
  return frcp(1.0f + fexp2(z * -1.4426950408889634f));
}
__device__ __forceinline__ float fexp(float x) { return fexp2(x * 1.4426950408889634f); }

// ---------------------------------------------------------------------------
// device section: merged GCN dense GEMM (data + query), bf16 MFMA
// ---------------------------------------------------------------------------
template <int KD>
__device__ __forceinline__ void dev_gemm(int blk, int tid, const ushort* __restrict__ Xd,
                                         const ushort* __restrict__ Xq,
                                         const ushort* __restrict__ WT,
                                         const float* __restrict__ dinv_d,
                                         const float* __restrict__ dinv_q,
                                         ushort* __restrict__ H) {
  int wave = tid >> 6, lane = tid & 63;
  int col = lane & 15, quad = lane >> 4;
  bool isQ = blk >= (cNd / 64);
  int mloc = (isQ ? blk - cNd / 64 : blk) * 64 + wave * 16;
  const ushort* X = isQ ? Xq : Xd;
  const float* dv = isQ ? dinv_q : dinv_d;
  size_t hbase = isQ ? (size_t)cNd : 0;
  floatx4 acc[8];
#pragma unroll
  for (int ct = 0; ct < 8; ++ct)
#pragma unroll
    for (int r = 0; r < 4; ++r) acc[ct][r] = 0.0f;
#pragma unroll
  for (int kc = 0; kc < KD / 32; ++kc) {
    bf16x8 a = *(const bf16x8*)(X + (size_t)(mloc + col) * KD + kc * 32 + quad * 8);
#pragma unroll
    for (int ct = 0; ct < 8; ++ct) {
      bf16x8 b = *(const bf16x8*)(WT + (size_t)(ct * 16 + col) * KD + kc * 32 + quad * 8);
      acc[ct] = __builtin_amdgcn_mfma_f32_16x16x32_bf16(a, b, acc[ct], 0, 0, 0);
    }
  }
  float sc[4];
#pragma unroll
  for (int r = 0; r < 4; ++r) sc[r] = dv[mloc + quad * 4 + r];
#pragma unroll
  for (int ct = 0; ct < 8; ++ct)
#pragma unroll
    for (int r = 0; r < 4; ++r)
      H[(hbase + mloc + quad * 4 + r) * 128 + ct * 16 + col] = f2bf(acc[ct][r] * sc[r]);
}

// ---------------------------------------------------------------------------
// device section: merged GCN aggregate (8 nodes/block, 32 lanes/node)
// ---------------------------------------------------------------------------
__device__ __forceinline__ void dev_gather(
    int blk, int tid, const ushort* __restrict__ htmp, const int* __restrict__ rp_d,
    const int* __restrict__ cnt_d, const int* __restrict__ col_d,
    const float* __restrict__ dinv_d, const int* __restrict__ rp_q,
    const int* __restrict__ cnt_q, const int* __restrict__ col_q,
    const float* __restrict__ dinv_q, const float* __restrict__ bias,
    ushort* __restrict__ dbf, ushort* __restrict__ qbf) {
  bool isQ = blk >= (cNd / 8);
  int node = (isQ ? blk - cNd / 8 : blk) * 8 + (tid >> 5);
  int l = tid & 31;
  const ushort* hs = htmp + (isQ ? (size_t)cNd * 128 : 0);
  const int* rp = isQ ? rp_q : rp_d;
  const int* cnt = isQ ? cnt_q : cnt_d;
  const int* col = isQ ? col_q : col_d;
  const float* dinv = isQ ? dinv_q : dinv_d;
  ushort* outp = isQ ? qbf : dbf;
  int c = cnt[node], s0 = rp[node];
  float dt = dinv[node];
  float4 acc = us4f4(*(const ushort4*)(hs + (size_t)node * 128 + l * 4));
  int cm = c < 32 ? c : 32;
  for (int j0 = 0; j0 < cm; j0 += 8) {
    int ss[8];
    ushort4 v[8];
#pragma unroll
    for (int t = 0; t < 8; ++t) {
      int jj = j0 + t;
      ss[t] = col[s0 + (jj < c ? jj : c - 1)];
    }
#pragma unroll
    for (int t = 0; t < 8; ++t)
      v[t] = *(const ushort4*)(hs + (size_t)ss[t] * 128 + l * 4);
#pragma unroll
    for (int t = 0; t < 8; ++t) {
      if (j0 + t < cm) {
        float4 f = us4f4(v[t]);
        acc.x += f.x; acc.y += f.y; acc.z += f.z; acc.w += f.w;
      }
    }
  }
  for (int j = 32; j < c; ++j) {
    int s = col[s0 + j];
    float4 f = us4f4(*(const ushort4*)(hs + (size_t)s * 128 + l * 4));
    acc.x += f.x; acc.y += f.y; acc.z += f.z; acc.w += f.w;
  }
  float4 bv = F4C(bias + l * 4);
  float4 r;
  r.x = fmaxf(acc.x * dt + bv.x, 0.0f);
  r.y = fmaxf(acc.y * dt + bv.y, 0.0f);
  r.z = fmaxf(acc.z * dt + bv.z, 0.0f);
  r.w = fmaxf(acc.w * dt + bv.w, 0.0f);
  *(ushort4*)(outp + (size_t)node * 128 + l * 4) = f4us4(r);
}

// ---------------------------------------------------------------------------
// device section: level prep (qw | logits | ld | lq), blk in [0,1792)
// ---------------------------------------------------------------------------
__device__ __forceinline__ void dev_prep(
    int blk, int tid, float* smem, const ushort* __restrict__ qbf,
    const ushort* __restrict__ dbf, const ushort* __restrict__ wnT,
    const ushort* __restrict__ vnbf, const float* __restrict__ Vn,
    ushort* __restrict__ qw, float* __restrict__ lgt, float* __restrict__ ldb,
    float* __restrict__ lqb) {
  int wave = tid >> 6, lane = tid & 63;
  int col = lane & 15, quad = lane >> 4;
  if (blk < 1024) {  // qW[b,k] = q[b] @ Wn[k]
    int b = blk >> 4, k = blk & 15;
    int et0 = wave * 2;
    floatx4 acc[2][2];
#pragma unroll
    for (int qt = 0; qt < 2; ++qt)
#pragma unroll
      for (int ei = 0; ei < 2; ++ei)
#pragma unroll
        for (int r = 0; r < 4; ++r) acc[qt][ei][r] = 0.0f;
#pragma unroll
    for (int kc = 0; kc < 4; ++kc) {
      bf16x8 a0 = *(const bf16x8*)(qbf + (size_t)(b * 32 + col) * 128 + kc * 32 + quad * 8);
      bf16x8 a1 = *(const bf16x8*)(qbf + (size_t)(b * 32 + 16 + col) * 128 + kc * 32 + quad * 8);
#pragma unroll
      for (int ei = 0; ei < 2; ++ei) {
        bf16x8 bf = *(const bf16x8*)(wnT + (size_t)(k * 128 + (et0 + ei) * 16 + col) * 128 +
                                     kc * 32 + quad * 8);
        acc[0][ei] = __builtin_amdgcn_mfma_f32_16x16x32_bf16(a0, bf, acc[0][ei], 0, 0, 0);
        acc[1][ei] = __builtin_amdgcn_mfma_f32_16x16x32_bf16(a1, bf, acc[1][ei], 0, 0, 0);
      }
    }
#pragma unroll
    for (int qt = 0; qt < 2; ++qt)
#pragma unroll
      for (int ei = 0; ei < 2; ++ei)
#pragma unroll
        for (int r = 0; r < 4; ++r)
          qw[((size_t)(b * 16 + k) << 12) + (qt * 16 + quad * 4 + r) * 128 +
             (et0 + ei) * 16 + col] = f2bf(acc[qt][ei][r]);
  } else if (blk < 1536) {  // raw scaled logits
    int b2 = blk - 1024;
    int b = b2 >> 3, nc = b2 & 7;
    int n = nc * 64 + wave * 16 + col;
    floatx4 acc[2];
#pragma unroll
    for (int qt = 0; qt < 2; ++qt)
#pragma unroll
      for (int r = 0; r < 4; ++r) acc[qt][r] = 0.0f;
#pragma unroll
    for (int kc = 0; kc < 4; ++kc) {
      bf16x8 bf = *(const bf16x8*)(dbf + ((size_t)(b * 512 + n) << 7) + kc * 32 + quad * 8);
      bf16x8 a0 = *(const bf16x8*)(qbf + (size_t)(b * 32 + col) * 128 + kc * 32 + quad * 8);
      bf16x8 a1 = *(const bf16x8*)(qbf + (size_t)(b * 32 + 16 + col) * 128 + kc * 32 + quad * 8);
      acc[0] = __builtin_amdgcn_mfma_f32_16x16x32_bf16(a0, bf, acc[0], 0, 0, 0);
      acc[1] = __builtin_amdgcn_mfma_f32_16x16x32_bf16(a1, bf, acc[1], 0, 0, 0);
    }
    const float sc = 0.088388347648318440550f;  // 1/sqrt(128)
#pragma unroll
    for (int qt = 0; qt < 2; ++qt)
#pragma unroll
      for (int r = 0; r < 4; ++r)
        lgt[((size_t)(b * 32 + qt * 16 + quad * 4 + r) << 9) + n] = acc[qt][r] * sc;
  } else if (blk < 1664) {  // ld[b,k,n] = d · Vn[k][128:]
    int b3 = blk - 1536;
    int b = b3 >> 1, half = b3 & 1;
    bf16x8 bfr[4];
#pragma unroll
    for (int kc = 0; kc < 4; ++kc)
      bfr[kc] = *(const bf16x8*)(vnbf + col * 256 + 128 + kc * 32 + quad * 8);
#pragma unroll
    for (int i = 0; i < 4; ++i) {
      int mt = half * 16 + wave * 4 + i;
      floatx4 acc;
#pragma unroll
      for (int r = 0; r < 4; ++r) acc[r] = 0.0f;
#pragma unroll
      for (int kc = 0; kc < 4; ++kc) {
        bf16x8 a = *(const bf16x8*)(dbf + ((size_t)(b * 512 + mt * 16 + col) << 7) +
                                    kc * 32 + quad * 8);
        acc = __builtin_amdgcn_mfma_f32_16x16x32_bf16(a, bfr[kc], acc, 0, 0, 0);
      }
#pragma unroll
      for (int r = 0; r < 4; ++r)
        ldb[((size_t)(b * 16 + col) << 9) + mt * 16 + quad * 4 + r] = acc[r];
    }
  } else {  // lq rowdot
    float* sh_r = smem;
    float* sh_v = smem + 16 * 132;
    int b4 = blk - 1664;
    int g0 = b4 * 16;
#pragma unroll
    for (int i = 0; i < 8; ++i) {
      int j = tid + 256 * i;
      int a = j >> 7, e = j & 127;
      sh_r[a * 132 + e] = bf2f(qbf[(size_t)(g0 + a) * 128 + e]);
      sh_v[a * 132 + e] = Vn[a * 256 + e];
    }
    __syncthreads();
    int r = tid & 15, k = tid >> 4;
    float s = 0.0f;
#pragma unroll 8
    for (int e = 0; e < 128; ++e) s += sh_r[r * 132 + e] * sh_v[k * 132 + e];
    int g = g0 + r;
    int b = g >> 5, rr = g & 31;
    lqb[((b * 16 + k) << 5) + rr] = s;
  }
}

// ---------------------------------------------------------------------------
// device section: NTN level (split-k x2), blk in [0,1024)
// ---------------------------------------------------------------------------
__device__ __forceinline__ void dev_level(
    int blk, int tid, float* smem, const ushort* __restrict__ qw,
    const ushort* __restrict__ dbf, const float* __restrict__ lqb,
    const float* __restrict__ ldb, const float* __restrict__ bn,
    const float* __restrict__ cw, const float* __restrict__ w_end, int o1, int o2,
    int do_facc, float* __restrict__ Ebuf, float* __restrict__ Fbuf) {
  float* s_ld = smem;        // 512
  float* s_lq = smem + 512;  // 256
  int wave = tid >> 6, lane = tid & 63;
  int kh = blk & 1;
  int rest = blk >> 1;
  int b = rest >> 3, nc = rest & 7;
  int k0 = kh * 8;
  int col = lane & 15, quad = lane >> 4;
  int nn = wave * 16 + col;
  int n = nc * 64 + nn;

#pragma unroll
  for (int i = 0; i < 2; ++i) {
    int j = tid + 256 * i;
    int kk = j >> 6, nl = j & 63;
    s_ld[j] = ldb[((b * 16 + k0 + kk) << 9) + nc * 64 + nl];
  }
  {
    int kk = tid >> 5, qq = tid & 31;
    s_lq[tid] = lqb[(b * 16 + k0 + kk) * 32 + qq];
  }
  __syncthreads();

  float bnk[8], cwk[8], wkk[8];
#pragma unroll
  for (int kk = 0; kk < 8; ++kk) {
    bnk[kk] = bn[k0 + kk];
    cwk[kk] = cw[k0 + kk];
    float w = 0.0f;
    if (do_facc) {
      w = w_end[o1 + k0 + kk];
      if (o2 >= 0) w += w_end[o2 + k0 + kk];
    }
    wkk[kk] = w;
  }

  const ushort* dptr = dbf + (((size_t)(b * 512 + n)) << 7) + quad * 8;
  bf16x8 bfr[4];
#pragma unroll
  for (int kc = 0; kc < 4; ++kc) bfr[kc] = *(const bf16x8*)(dptr + kc * 32);

  const ushort* qwb = qw + ((size_t)b << 16) + (k0 << 12) + quad * 8;
  floatx4 eacc[2], facc[2];
#pragma unroll
  for (int t = 0; t < 2; ++t)
#pragma unroll
    for (int r = 0; r < 4; ++r) { eacc[t][r] = 0.0f; facc[t][r] = 0.0f; }

#pragma unroll 2
  for (int kk = 0; kk < 8; ++kk) {
    const ushort* qk = qwb + (kk << 12);
    floatx4 bil[2];
#pragma unroll
    for (int t = 0; t < 2; ++t)
#pragma unroll
      for (int r = 0; r < 4; ++r) bil[t][r] = 0.0f;
#pragma unroll
    for (int kc = 0; kc < 4; ++kc) {
      bf16x8 a0 = *(const bf16x8*)(qk + (col << 7) + kc * 32);
      bf16x8 a1 = *(const bf16x8*)(qk + ((col + 16) << 7) + kc * 32);
      bil[0] = __builtin_amdgcn_mfma_f32_16x16x32_bf16(a0, bfr[kc], bil[0], 0, 0, 0);
      bil[1] = __builtin_amdgcn_mfma_f32_16x16x32_bf16(a1, bfr[kc], bil[1], 0, 0, 0);
    }
    float ldv = s_ld[kk * 64 + nn] + bnk[kk];
#pragma unroll
    for (int t = 0; t < 2; ++t) {
#pragma unroll
      for (int r = 0; r < 4; ++r) {
        float lqv = s_lq[kk * 32 + t * 16 + quad * 4 + r];
        float sg = fsigmoid(bil[t][r] + lqv + ldv);
        eacc[t][r] += cwk[kk] * sg;
        facc[t][r] += wkk[kk] * sg;
      }
    }
  }

  float* Ep = Ebuf + (size_t)kh * cSZ;
  float* Fp = Fbuf + (size_t)kh * cSZ;
#pragma unroll
  for (int t = 0; t < 2; ++t) {
#pragma unroll
    for (int r = 0; r < 4; ++r) {
      size_t idx = ((size_t)(b * 32 + t * 16 + quad * 4 + r) << 9) + n;
      Ep[idx] = eacc[t][r];
      if (do_facc) Fp[idx] = facc[t][r];
    }
  }
}

// ---------------------------------------------------------------------------
// device section: combine (att softmax + weighted accumulate / final softmax)
// ---------------------------------------------------------------------------
__device__ __forceinline__ void dev_combine(
    int blk, int tid, float* sh, const float* __restrict__ lgt,
    const float* __restrict__ Ebuf, const float* __restrict__ Fbuf,
    float* __restrict__ accb, const float* __restrict__ w_end,
    const float* __restrict__ b_end, int widx, int do_sm, int hasF, int mode,
    float* __restrict__ out) {
  size_t base = (size_t)blk * 512;
  size_t i0 = base + tid, i1 = i0 + 256;
  float w = w_end[widx];
  float l0 = lgt[i0], l1 = lgt[i1];
  float m = fmaxf(l0, l1);
#pragma unroll
  for (int o = 32; o; o >>= 1) m = fmaxf(m, __shfl_xor(m, o, 64));
  if ((tid & 63) == 0) sh[tid >> 6] = m;
  __syncthreads();
  m = fmaxf(fmaxf(sh[0], sh[1]), fmaxf(sh[2], sh[3]));
  float e0 = fexp(l0 - m), e1 = fexp(l1 - m);
  float s = e0 + e1;
#pragma unroll
  for (int o = 32; o; o >>= 1) s += __shfl_xor(s, o, 64);
  if ((tid & 63) == 0) sh[4 + (tid >> 6)] = s;
  __syncthreads();
  s = sh[4] + sh[5] + sh[6] + sh[7];
  float ainv = frcp(s);
  float a0 = e0 * ainv, a1 = e1 * ainv;
  __syncthreads();
  float v0 = a0 * (Ebuf[i0] + Ebuf[i0 + cSZ]);
  float v1 = a1 * (Ebuf[i1] + Ebuf[i1 + cSZ]);
  float f0 = 0.0f, f1 = 0.0f;
  if (hasF) {
    f0 = a0 * (Fbuf[i0] + Fbuf[i0 + cSZ]);
    f1 = a1 * (Fbuf[i1] + Fbuf[i1 + cSZ]);
  }
  if (do_sm) {
    float mm = fmaxf(v0, v1);
#pragma unroll
    for (int o = 32; o; o >>= 1) mm = fmaxf(mm, __shfl_xor(mm, o, 64));
    if ((tid & 63) == 0) sh[tid >> 6] = mm;
    __syncthreads();
    mm = fmaxf(fmaxf(sh[0], sh[1]), fmaxf(sh[2], sh[3]));
    float ee0 = fexp(v0 - mm), ee1 = fexp(v1 - mm);
    float ss = ee0 + ee1;
#pragma unroll
    for (int o = 32; o; o >>= 1) ss += __shfl_xor(ss, o, 64);
    if ((tid & 63) == 0) sh[4 + (tid >> 6)] = ss;
    __syncthreads();
    ss = sh[4] + sh[5] + sh[6] + sh[7];
    float inv = frcp(ss);
    v0 = ee0 * inv;
    v1 = ee1 * inv;
    __syncthreads();
  }
  float t0 = w * v0 + f0, t1 = w * v1 + f1;
  if (mode == 0) {
    accb[i0] = t0;
    accb[i1] = t1;
  } else if (mode == 1) {
    accb[i0] += t0;
    accb[i1] += t1;
  } else {
    float be = b_end[0];
    float z0 = accb[i0] + t0 + be, z1 = accb[i1] + t1 + be;
    float mm = fmaxf(z0, z1);
#pragma unroll
    for (int o = 32; o; o >>= 1) mm = fmaxf(mm, __shfl_xor(mm, o, 64));
    if ((tid & 63) == 0) sh[tid >> 6] = mm;
    __syncthreads();
    mm = fmaxf(fmaxf(sh[0], sh[1]), fmaxf(sh[2], sh[3]));
    float ee0 = fexp(z0 - mm), ee1 = fexp(z1 - mm);
    float ss = ee0 + ee1;
#pragma unroll
    for (int o = 32; o; o >>= 1) ss += __shfl_xor(ss, o, 64);
    if ((tid & 63) == 0) sh[4 + (tid >> 6)] = ss;
    __syncthreads();
    ss = sh[4] + sh[5] + sh[6] + sh[7];
    float inv = frcp(ss);
    out[i0] = ee0 * inv;
    out[i1] = ee1 * inv;
  }
}

// ---------------------------------------------------------------------------
// D1: conversions + weight transposes + edge counts (4084 blocks)
// ---------------------------------------------------------------------------
__global__ __launch_bounds__(256) void k_front(
    const float* __restrict__ xd, const float* __restrict__ xq,
    const float* __restrict__ v0, const float* __restrict__ v1,
    const float* __restrict__ v2, ushort* __restrict__ oxd, ushort* __restrict__ oxq,
    ushort* __restrict__ ov0, ushort* __restrict__ ov1, ushort* __restrict__ ov2,
    const float* __restrict__ W1, const float* __restrict__ W2,
    const float* __restrict__ W3, const float* __restrict__ Wn0,
    const float* __restrict__ Wn1, const float* __restrict__ Wn2,
    ushort* __restrict__ o1, ushort* __restrict__ o2, ushort* __restrict__ o3,
    ushort* __restrict__ on0, ushort* __restrict__ on1, ushort* __restrict__ on2,
    const int* __restrict__ dst_d, const int* __restrict__ dst_q,
    int* __restrict__ cnt_d, int* __restrict__ cnt_q) {
  __shared__ float tile[32][33];
  int blk = blockIdx.x, tid = threadIdx.x;
  if (blk < NB_CVT) {
    const float* src;
    ushort* dst;
    int i;
    if (blk < 2048) { src = xd; dst = oxd; i = blk * 256 + tid; }
    else if (blk < 2176) { src = xq; dst = oxq; i = (blk - 2048) * 256 + tid; }
    else if (blk < 2180) { src = v0; dst = ov0; i = (blk - 2176) * 256 + tid; }
    else if (blk < 2184) { src = v1; dst = ov1; i = (blk - 2180) * 256 + tid; }
    else { src = v2; dst = ov2; i = (blk - 2184) * 256 + tid; }
    *(ushort4*)(dst + (size_t)i * 4) = f4us4(F4C(src + (size_t)i * 4));
  } else if (blk < NB_CVT + NB_T2BF) {
    int b5 = blk - NB_CVT;
    const float* in;
    ushort* out;
    int R, C, bt, t;
    if (b5 < 8)        { in = W1;  out = o1;  R = 64;  C = 128; bt = 0; t = b5; }
    else if (b5 < 24)  { in = W2;  out = o2;  R = 128; C = 128; bt = 0; t = b5 - 8; }
    else if (b5 < 40)  { in = W3;  out = o3;  R = 128; C = 128; bt = 0; t = b5 - 24; }
    else if (b5 < 296) { in = Wn0; out = on0; R = 128; C = 128; bt = (b5 - 40) >> 4;  t = (b5 - 40) & 15; }
    else if (b5 < 552) { in = Wn1; out = on1; R = 128; C = 128; bt = (b5 - 296) >> 4; t = (b5 - 296) & 15; }
    else               { in = Wn2; out = on2; R = 128; C = 128; bt = (b5 - 552) >> 4; t = (b5 - 552) & 15; }
    int tilesC = C >> 5;
    int tr = t / tilesC, tc = t - tr * tilesC;
    int tx = tid & 31, ty = tid >> 5;
    const float* ib = in + (size_t)bt * R * C;
    ushort* ob = out + (size_t)bt * R * C;
#pragma unroll
    for (int i = 0; i < 4; ++i)
      tile[ty + i * 8][tx] = ib[(tr * 32 + ty + i * 8) * C + tc * 32 + tx];
    __syncthreads();
#pragma unroll
    for (int i = 0; i < 4; ++i)
      ob[(size_t)(tc * 32 + ty + i * 8) * R + tr * 32 + tx] = f2bf(tile[tx][ty + i * 8]);
  } else {
    int i = (blk - NB_CVT - NB_T2BF) * 256 + tid;
    if (i < cEd) atomicAdd(&cnt_d[dst_d[i]], 1);
    else atomicAdd(&cnt_q[dst_q[i - cEd]], 1);
  }
}

// ---------------------------------------------------------------------------
// D2: single-pass chained scan (34 blocks) + dinv (34 blocks). 68 x 1024.
// ---------------------------------------------------------------------------
__global__ __launch_bounds__(1024) void k_scan_dinv(
    const int* __restrict__ cnt_d, const int* __restrict__ cnt_q,
    int* __restrict__ rp_d, int* __restrict__ rp_q, float* __restrict__ dinv_d,
    float* __restrict__ dinv_q, int* flags, int* vals) {
  int blk = blockIdx.x, tid = threadIdx.x;
  if (blk < 34) {
    __shared__ int sh[1024];
    __shared__ int s_pref;
    bool isQ = blk >= 32;
    int seg0 = isQ ? 32 : 0;
    const int* cnt = isQ ? cnt_q : cnt_d;
    int* rp = isQ ? rp_q : rp_d;
    int base = (blk - seg0) * 1024;
    int v = cnt[base + tid];
    sh[tid] = v;
    __syncthreads();
    for (int off = 1; off < 1024; off <<= 1) {
      int t = (tid >= off) ? sh[tid - off] : 0;
      __syncthreads();
      sh[tid] += t;
      __syncthreads();
    }
    if (tid == 0) {
      int prefix = 0;
      if (blk != seg0) {
        while (atomicAdd(&flags[blk - 1], 0) == 0) {}
        __threadfence();
        prefix = atomicAdd(&vals[blk - 1], 0);
      }
      atomicExch(&vals[blk], prefix + sh[1023]);
      __threadfence();
      atomicExch(&flags[blk], 1);
      s_pref = prefix;
    }
    __syncthreads();
    rp[base + tid] = s_pref + sh[tid] - v;
  } else {
    int b2 = blk - 34;
    if (b2 < 32) {
      int i = b2 * 1024 + tid;
      dinv_d[i] = 1.0f / sqrtf((float)(cnt_d[i] + 1));
    } else {
      int i = (b2 - 32) * 1024 + tid;
      dinv_q[i] = 1.0f / sqrtf((float)(cnt_q[i] + 1));
    }
  }
}

// ---------------------------------------------------------------------------
// D3: CSR fill + GCN GEMM layer 1 (KD=64). 1632 blocks.
// ---------------------------------------------------------------------------
__global__ __launch_bounds__(256) void k_fill_gemm1(
    const int* __restrict__ src_d, const int* __restrict__ dst_d,
    const int* __restrict__ src_q, const int* __restrict__ dst_q,
    const int* __restrict__ rp_d, const int* __restrict__ rp_q,
    int* __restrict__ cur_d, int* __restrict__ cur_q, int* __restrict__ col_d,
    int* __restrict__ col_q, const ushort* __restrict__ xdbf,
    const ushort* __restrict__ xqbf, const ushort* __restrict__ w1T,
    const float* __restrict__ dinv_d, const float* __restrict__ dinv_q,
    ushort* __restrict__ htmp) {
  int blk = blockIdx.x, tid = threadIdx.x;
  if (blk < NB_FILL) {
    int i = blk * 256 + tid;
    if (i < cEd) {
      int d = dst_d[i];
      int p = atomicAdd(&cur_d[d], 1);
      col_d[rp_d[d] + p] = src_d[i];
    } else {
      int j = i - cEd;
      int d = dst_q[j];
      int p = atomicAdd(&cur_q[d], 1);
      col_q[rp_q[d] + p] = src_q[j];
    }
  } else {
    dev_gemm<64>(blk - NB_FILL, tid, xdbf, xqbf, w1T, dinv_d, dinv_q, htmp);
  }
}

// ---------------------------------------------------------------------------
// level (+ optional gather).  grid = nb_level + (do_gather ? 4352 : 0)
// ---------------------------------------------------------------------------
__global__ __launch_bounds__(256, 4) void k_lev(
    int nb_level, const ushort* __restrict__ qw, const ushort* __restrict__ dbf_lev,
    const float* __restrict__ lqb, const float* __restrict__ ldb,
    const float* __restrict__ bn, const float* __restrict__ cw,
    const float* __restrict__ w_end, int o1, int o2, int do_facc,
    float* __restrict__ Ebuf, float* __restrict__ Fbuf,
    const ushort* __restrict__ htmp, const int* __restrict__ rp_d,
    const int* __restrict__ cnt_d, const int* __restrict__ col_d,
    const float* __restrict__ dinv_d, const int* __restrict__ rp_q,
    const int* __restrict__ cnt_q, const int* __restrict__ col_q,
    const float* __restrict__ dinv_q, const float* __restrict__ bias,
    ushort* __restrict__ dbf_out, ushort* __restrict__ qbf_out) {
  __shared__ float smem[768];
  int blk = blockIdx.x, tid = threadIdx.x;
  if (blk < nb_level) {
    dev_level(blk, tid, smem, qw, dbf_lev, lqb, ldb, bn, cw, w_end, o1, o2, do_facc,
              Ebuf, Fbuf);
  } else {
    dev_gather(blk - nb_level, tid, htmp, rp_d, cnt_d, col_d, dinv_d, rp_q, cnt_q,
               col_q, dinv_q, bias, dbf_out, qbf_out);
  }
}

// ---------------------------------------------------------------------------
// combine (+ optional prep + optional gemm128)
// grid = nb_comb + nb_prep + nb_gemm
// ---------------------------------------------------------------------------
__global__ __launch_bounds__(256, 4) void k_mid(
    int nb_comb, int nb_prep, const float* __restrict__ lgt_c,
    const float* __restrict__ Ebuf, const float* __restrict__ Fbuf,
    float* __restrict__ accb, const float* __restrict__ w_end,
    const float* __restrict__ b_end, int widx, int do_sm, int hasF, int mode,
    float* __restrict__ out, const ushort* __restrict__ qbf_p,
    const ushort* __restrict__ dbf_p, const ushort* __restrict__ wnT,
    const ushort* __restrict__ vnbf, const float* __restrict__ Vn,
    ushort* __restrict__ qw_p, float* __restrict__ lgt_p, float* __restrict__ ldb_p,
    float* __restrict__ lqb_p, const ushort* __restrict__ gXd,
    const ushort* __restrict__ gXq, const ushort* __restrict__ gWT,
    const float* __restrict__ dinv_d, const float* __restrict__ dinv_q,
    ushort* __restrict__ htmp) {
  __shared__ float smem[4224];
  int blk = blockIdx.x, tid = threadIdx.x;
  if (blk < nb_comb) {
    dev_combine(blk, tid, smem, lgt_c, Ebuf, Fbuf, accb, w_end, b_end, widx, do_sm,
                hasF, mode, out);
  } else if (blk < nb_comb + nb_prep) {
    dev_prep(blk - nb_comb, tid, smem, qbf_p, dbf_p, wnT, vnbf, Vn, qw_p, lgt_p,
             ldb_p, lqb_p);
  } else {
    dev_gemm<128>(blk - nb_comb - nb_prep, tid, gXd, gXq, gWT, dinv_d, dinv_q, htmp);
  }
}

// ---------------------------------------------------------------------------
// Host orchestration — 12 dispatches (1 memset + 11 kernels)
// ---------------------------------------------------------------------------
extern "C" void kernel_launch(void* const* d_in, const int* in_sizes, int n_in,
                              void* d_out, int out_size, void* d_ws, size_t ws_size,
                              hipStream_t stream) {
  (void)in_sizes; (void)n_in; (void)out_size; (void)ws_size;
  const float* x_d = (const float*)d_in[0];
  const float* x_q = (const float*)d_in[1];
  const int* ei_d = (const int*)d_in[2];
  const int* ei_q = (const int*)d_in[3];
  const float* W1 = (const float*)d_in[6];
  const float* b1 = (const float*)d_in[7];
  const float* W2 = (const float*)d_in[8];
  const float* b2 = (const float*)d_in[9];
  const float* W3 = (const float*)d_in[10];
  const float* b3 = (const float*)d_in[11];
  const float* Wn[3] = {(const float*)d_in[12], (const float*)d_in[17], (const float*)d_in[22]};
  const float* Vn[3] = {(const float*)d_in[13], (const float*)d_in[18], (const float*)d_in[23]};
  const float* bn[3] = {(const float*)d_in[14], (const float*)d_in[19], (const float*)d_in[24]};
  const float* cw[3] = {(const float*)d_in[15], (const float*)d_in[20], (const float*)d_in[25]};
  const float* w_end = (const float*)d_in[27];
  const float* b_end = (const float*)d_in[28];
  float* out = (float*)d_out;

  char* wsp = (char*)d_ws;
  auto alloc = [&](size_t nbytes) {
    void* p = (void*)wsp;
    wsp += (nbytes + 255) & ~(size_t)255;
    return p;
  };
  // zero region: cnt_d,cnt_q,cur_d,cur_q,flags,vals (contiguous, 256-mult sizes)
  int* cnt_d = (int*)alloc(cNd * 4);
  int* cnt_q = (int*)alloc(cNq * 4);
  int* cur_d = (int*)alloc(cNd * 4);
  int* cur_q = (int*)alloc(cNq * 4);
  int* flags = (int*)alloc(64 * 4);
  int* vals = (int*)alloc(64 * 4);
  size_t zbytes = (size_t)2 * (cNd + cNq) * 4 + 512;
  float* dinv_d = (float*)alloc(cNd * 4);
  float* dinv_q = (float*)alloc(cNq * 4);
  int* rp_d = (int*)alloc(cNd * 4);
  int* rp_q = (int*)alloc(cNq * 4);
  int* col_d = (int*)alloc((size_t)cEd * 4);
  int* col_q = (int*)alloc((size_t)cEq * 4);
  ushort* xdbf = (ushort*)alloc((size_t)cNd * 64 * 2);
  ushort* xqbf = (ushort*)alloc((size_t)cNq * 64 * 2);
  ushort* w1T = (ushort*)alloc(128 * 64 * 2);
  ushort* w2T = (ushort*)alloc(128 * 128 * 2);
  ushort* w3T = (ushort*)alloc(128 * 128 * 2);
  ushort* wnT[3];
  for (int l = 0; l < 3; ++l) wnT[l] = (ushort*)alloc((size_t)16 * 128 * 128 * 2);
  ushort* vnbf[3];
  for (int l = 0; l < 3; ++l) vnbf[l] = (ushort*)alloc(16 * 256 * 2);
  ushort* htmp = (ushort*)alloc((size_t)(cNd + cNq) * 128 * 2);
  ushort* dbf[2];
  for (int p = 0; p < 2; ++p) dbf[p] = (ushort*)alloc((size_t)cNd * 128 * 2);
  ushort* qbf[3];
  for (int l = 0; l < 3; ++l) qbf[l] = (ushort*)alloc((size_t)cNq * 128 * 2);
  float* lgt[2];
  for (int p = 0; p < 2; ++p) lgt[p] = (float*)alloc(cSZ * 4);
  float* Ebuf[2];
  for (int p = 0; p < 2; ++p) Ebuf[p] = (float*)alloc(cSZ * 2 * 4);
  float* Fbuf[2];
  for (int p = 0; p < 2; ++p) Fbuf[p] = (float*)alloc(cSZ * 2 * 4);
  float* accb = (float*)alloc(cSZ * 4);
  float* lqb[2];
  for (int p = 0; p < 2; ++p) lqb[p] = (float*)alloc((size_t)cB * 16 * 32 * 4);
  float* ldb[2];
  for (int p = 0; p < 2; ++p) ldb[p] = (float*)alloc((size_t)cB * 16 * 512 * 4);
  ushort* qw[2];
  for (int p = 0; p < 2; ++p) qw[p] = (ushort*)alloc((size_t)cB * 16 * 32 * 128 * 2);

  const int* src_d = ei_d;
  const int* dst_d = ei_d + cEd;
  const int* src_q = ei_q;
  const int* dst_q = ei_q + cEq;

  hipMemsetAsync(cnt_d, 0, zbytes, stream);

  // D1: conversions + transposes + counts
  k_front<<<NB_CVT + NB_T2BF + NB_CNT, 256, 0, stream>>>(
      x_d, x_q, Vn[0], Vn[1], Vn[2], xdbf, xqbf, vnbf[0], vnbf[1], vnbf[2], W1, W2,
      W3, Wn[0], Wn[1], Wn[2], w1T, w2T, w3T, wnT[0], wnT[1], wnT[2], dst_d, dst_q,
      cnt_d, cnt_q);

  // D2: scan + dinv
  k_scan_dinv<<<68, 1024, 0, stream>>>(cnt_d, cnt_q, rp_d, rp_q, dinv_d, dinv_q,
                                       flags, vals);

  // D3: fill + gemm layer 1
  k_fill_gemm1<<<NB_FILL + NB_GEMM, 256, 0, stream>>>(
      src_d, dst_d, src_q, dst_q, rp_d, rp_q, cur_d, cur_q, col_d, col_q, xdbf, xqbf,
      w1T, dinv_d, dinv_q, htmp);

  // D4: gather layer 1 -> dbf[0], qbf[0]
  k_lev<<<NB_GATH, 256, 0, stream>>>(0, qw[0], dbf[0], lqb[0], ldb[0], bn[0], cw[0],
                                     w_end, 0, -1, 0, Ebuf[0], Fbuf[0], htmp, rp_d,
                                     cnt_d, col_d, dinv_d, rp_q, cnt_q, col_q, dinv_q,
                                     b1, dbf[0], qbf[0]);

  // D5: prep level1 (p0) + gemm layer2
  k_mid<<<NB_PREP + NB_GEMM, 256, 0, stream>>>(
      0, NB_PREP, lgt[0], Ebuf[0], Fbuf[0], accb, w_end, b_end, 0, 0, 0, 0, out,
      qbf[0], dbf[0], wnT[0], vnbf[0], Vn[0], qw[0], lgt[0], ldb[0], lqb[0], dbf[0],
      qbf[0], w2T, dinv_d, dinv_q, htmp);

  // D6: level1 (p0) + gather layer2 -> dbf[1], qbf[1]
  k_lev<<<NB_LEVEL + NB_GATH, 256, 0, stream>>>(
      NB_LEVEL, qw[0], dbf[0], lqb[0], ldb[0], bn[0], cw[0], w_end, 0, -1, 0,
      Ebuf[0], Fbuf[0], htmp, rp_d, cnt_d, col_d, dinv_d, rp_q, cnt_q, col_q, dinv_q,
      b2, dbf[1], qbf[1]);

  // D7: combine1 (lgt0,E0,F0; mode init) + prep level2 (p1) + gemm layer3
  k_mid<<<NB_COMB + NB_PREP + NB_GEMM, 256, 0, stream>>>(
      NB_COMB, NB_PREP, lgt[0], Ebuf[0], Fbuf[0], accb, w_end, b_end, 0, 1, 0, 0,
      out, qbf[1], dbf[1], wnT[1], vnbf[1], Vn[1], qw[1], lgt[1], ldb[1], lqb[1],
      dbf[1], qbf[1], w3T, dinv_d, dinv_q, htmp);

  // D8: level2 (p1) + gather layer3 -> dbf[0], qbf[2]
  k_lev<<<NB_LEVEL + NB_GATH, 256, 0, stream>>>(
      NB_LEVEL, qw[1], dbf[1], lqb[1], ldb[1], bn[1], cw[1], w_end, 19, -1, 1,
      Ebuf[1], Fbuf[1], htmp, rp_d, cnt_d, col_d, dinv_d, rp_q, cnt_q, col_q, dinv_q,
      b3, dbf[0], qbf[2]);

  // D9: combine2 (lgt1,E1,F1; raw e2, mode +=) + prep level3 (p0)
  k_mid<<<NB_COMB + NB_PREP, 256, 0, stream>>>(
      NB_COMB, NB_PREP, lgt[1], Ebuf[1], Fbuf[1], accb, w_end, b_end, 1, 0, 1, 1,
      out, qbf[2], dbf[0], wnT[2], vnbf[2], Vn[2], qw[0], lgt[0], ldb[0], lqb[0],
      dbf[0], qbf[2], w3T, dinv_d, dinv_q, htmp);

  // D10: level3 (p0)
  k_lev<<<NB_LEVEL, 256, 0, stream>>>(
      NB_LEVEL, qw[0], dbf[0], lqb[0], ldb[0], bn[2], cw[2], w_end, 3, 35, 1,
      Ebuf[0], Fbuf[0], htmp, rp_d, cnt_d, col_d, dinv_d, rp_q, cnt_q, col_q, dinv_q,
      b3, dbf[1], qbf[2]);

  // D11: combine3 (lgt0,E0,F0; mode final -> out)
  k_mid<<<NB_COMB, 256, 0, stream>>>(
      NB_COMB, 0, lgt[0], Ebuf[0], Fbuf[0], accb, w_end, b_end, 2, 1, 1, 2, out,
      qbf[2], dbf[0], wnT[2], vnbf[2], Vn[2], qw[0], lgt[0], ldb[0], lqb[0], dbf[0],
      qbf[2], w3T, dinv_d, dinv_q, htmp);
}

// Round 7
// 398.286 us; speedup vs baseline: 1.1128x; 1.1128x over previous
//
#include <hip/hip_runtime.h>
#include <math.h>

// ---------------------------------------------------------------------------
// Problem constants (fixed production sizes from the reference)
// ---------------------------------------------------------------------------
namespace {
constexpr int cB  = 64;
constexpr int cNQ = 32;
constexpr int cND = 512;
constexpr int cNd = cB * cND;   // 32768
constexpr int cNq = cB * cNQ;   // 2048
constexpr int cEd = cNd * 8;    // 262144
constexpr int cEq = cNq * 8;    // 16384
constexpr size_t cSZ = (size_t)cB * cNQ * cND;  // 1M
}

#define F4C(p) (*(const float4*)(p))
#define F4W(p) (*(float4*)(p))

typedef __attribute__((ext_vector_type(8))) __bf16 bf16x8;
typedef __attribute__((ext_vector_type(4))) float floatx4;

__device__ __forceinline__ ushort f2bf(float f) {
  union { float f; unsigned u; } v;
  v.f = f;
  unsigned u = v.u;
  return (ushort)((u + 0x7fffu + ((u >> 16) & 1u)) >> 16);
}
__device__ __forceinline__ float bf2f(ushort u) {
  union { unsigned u; float f; } v;
  v.u = ((unsigned)u) << 16;
  return v.f;
}
__device__ __forceinline__ float4 us4f4(ushort4 u) {
  return make_float4(bf2f(u.x), bf2f(u.y), bf2f(u.z), bf2f(u.w));
}
__device__ __forceinline__ ushort4 f4us4(float4 f) {
  ushort4 o;
  o.x = f2bf(f.x); o.y = f2bf(f.y); o.z = f2bf(f.z); o.w = f2bf(f.w);
  return o;
}
__device__ __forceinline__ float fexp2(float x) {
#if __has_builtin(__builtin_amdgcn_exp2f)
  return __builtin_amdgcn_exp2f(x);
#else
  return exp2f(x);
#endif
}
__device__ __forceinline__ float frcp(float x) {
#if __has_builtin(__builtin_amdgcn_rcpf)
  return __builtin_amdgcn_rcpf(x);
#else
  return 1.0f / x;
#endif
}
__device__ __forceinline__ float fsigmoid(float z) {
  return frcp(1.0f + fexp2(z * -1.4426950408889634f));
}
__device__ __forceinline__ float fexp(float x) { return fexp2(x * 1.4426950408889634f); }

// XCD-affinity swizzle: for a section of 64*S blocks, graph g is handled only
// by blocks with blk%8 == g%8 (blockIdx -> XCD is round-robin %8 on MI355X).
// g = ((blk>>3)&7)*8 + (blk&7);  sub = blk>>6  (0..S-1)
__device__ __forceinline__ int swz_g(int j) { return (((j >> 3) & 7) << 3) | (j & 7); }

// ---------------------------------------------------------------------------
// Fused conversions (grid 2188)
// ---------------------------------------------------------------------------
__global__ void gmn_cvt_all(const float* __restrict__ xd, const float* __restrict__ xq,
                            const float* __restrict__ v0, const float* __restrict__ v1,
                            const float* __restrict__ v2, ushort* __restrict__ oxd,
                            ushort* __restrict__ oxq, ushort* __restrict__ ov0,
                            ushort* __restrict__ ov1, ushort* __restrict__ ov2) {
  int blk = blockIdx.x, tid = threadIdx.x;
  const float* src;
  ushort* dst;
  int i;
  if (blk < 2048) { src = xd; dst = oxd; i = blk * 256 + tid; }
  else if (blk < 2176) { src = xq; dst = oxq; i = (blk - 2048) * 256 + tid; }
  else if (blk < 2180) { src = v0; dst = ov0; i = (blk - 2176) * 256 + tid; }
  else if (blk < 2184) { src = v1; dst = ov1; i = (blk - 2180) * 256 + tid; }
  else { src = v2; dst = ov2; i = (blk - 2184) * 256 + tid; }
  *(ushort4*)(dst + (size_t)i * 4) = f4us4(F4C(src + (size_t)i * 4));
}

// ---------------------------------------------------------------------------
// Fused transpose+convert weights (grid 808)
// ---------------------------------------------------------------------------
__global__ __launch_bounds__(256) void gmn_t2bf_all(
    const float* __restrict__ W1, const float* __restrict__ W2,
    const float* __restrict__ W3, const float* __restrict__ Wn0,
    const float* __restrict__ Wn1, const float* __restrict__ Wn2,
    ushort* __restrict__ o1, ushort* __restrict__ o2, ushort* __restrict__ o3,
    ushort* __restrict__ on0, ushort* __restrict__ on1, ushort* __restrict__ on2) {
  __shared__ float tile[32][33];
  int blk = blockIdx.x;
  const float* in;
  ushort* out;
  int R, C, bt, t;
  if (blk < 8)        { in = W1;  out = o1;  R = 64;  C = 128; bt = 0; t = blk; }
  else if (blk < 24)  { in = W2;  out = o2;  R = 128; C = 128; bt = 0; t = blk - 8; }
  else if (blk < 40)  { in = W3;  out = o3;  R = 128; C = 128; bt = 0; t = blk - 24; }
  else if (blk < 296) { in = Wn0; out = on0; R = 128; C = 128; bt = (blk - 40) >> 4;  t = (blk - 40) & 15; }
  else if (blk < 552) { in = Wn1; out = on1; R = 128; C = 128; bt = (blk - 296) >> 4; t = (blk - 296) & 15; }
  else                { in = Wn2; out = on2; R = 128; C = 128; bt = (blk - 552) >> 4; t = (blk - 552) & 15; }
  int tilesC = C >> 5;
  int tr = t / tilesC, tc = t - tr * tilesC;
  int tx = threadIdx.x & 31, ty = threadIdx.x >> 5;
  const float* ib = in + (size_t)bt * R * C;
  ushort* ob = out + (size_t)bt * R * C;
#pragma unroll
  for (int i = 0; i < 4; ++i)
    tile[ty + i * 8][tx] = ib[(tr * 32 + ty + i * 8) * C + tc * 32 + tx];
  __syncthreads();
#pragma unroll
  for (int i = 0; i < 4; ++i)
    ob[(size_t)(tc * 32 + ty + i * 8) * R + tr * 32 + tx] = f2bf(tile[tx][ty + i * 8]);
}

// ---------------------------------------------------------------------------
// CSR construction (merged d+q)
// ---------------------------------------------------------------------------
__global__ void gmn_count_both(const int* __restrict__ dst_d, const int* __restrict__ dst_q,
                               int* __restrict__ cnt_d, int* __restrict__ cnt_q) {
  int i = blockIdx.x * 256 + threadIdx.x;
  if (i < cEd) atomicAdd(&cnt_d[dst_d[i]], 1);
  else atomicAdd(&cnt_q[dst_q[i - cEd]], 1);
}

__global__ __launch_bounds__(1024) void gmn_scan_local_both(
    const int* __restrict__ cnt_d, const int* __restrict__ cnt_q,
    int* __restrict__ rp_d, int* __restrict__ rp_q, int* __restrict__ bsum) {
  __shared__ int sh[1024];
  int blk = blockIdx.x, tid = threadIdx.x;
  bool isQ = blk >= 32;
  const int* cnt = isQ ? cnt_q : cnt_d;
  int* rp = isQ ? rp_q : rp_d;
  int base = (isQ ? blk - 32 : blk) * 1024;
  int v = cnt[base + tid];
  sh[tid] = v;
  __syncthreads();
  for (int off = 1; off < 1024; off <<= 1) {
    int t = (tid >= off) ? sh[tid - off] : 0;
    __syncthreads();
    sh[tid] += t;
    __syncthreads();
  }
  rp[base + tid] = sh[tid] - v;  // exclusive
  if (tid == 1023) bsum[blk] = sh[1023];
}

__global__ void gmn_scan_off_both(int* __restrict__ bsum) {
  int l = threadIdx.x;
  bool valid = l < 34;
  int v = valid ? bsum[l] : 0;
  int orig = v;
#pragma unroll
  for (int off = 1; off < 32; off <<= 1) {
    int t = __shfl_up(v, off, 32);
    if ((l & 31) >= off) v += t;
  }
  if (valid) bsum[l] = v - orig;  // exclusive within each 32-group
}

__global__ __launch_bounds__(1024) void gmn_scan_add_both(int* __restrict__ rp_d,
                                                          int* __restrict__ rp_q,
                                                          const int* __restrict__ bsum) {
  int blk = blockIdx.x, tid = threadIdx.x;
  if (blk < 32) rp_d[blk * 1024 + tid] += bsum[blk];
  else rp_q[(blk - 32) * 1024 + tid] += bsum[blk];
}

__global__ void gmn_dinv_both(const int* __restrict__ cnt_d, const int* __restrict__ cnt_q,
                              float* __restrict__ dinv_d, float* __restrict__ dinv_q) {
  int i = blockIdx.x * 256 + threadIdx.x;
  if (i < cNd) dinv_d[i] = 1.0f / sqrtf((float)(cnt_d[i] + 1));
  else { int j = i - cNd; dinv_q[j] = 1.0f / sqrtf((float)(cnt_q[j] + 1)); }
}

__global__ void gmn_fill_both(const int* __restrict__ src_d, const int* __restrict__ dst_d,
                              const int* __restrict__ src_q, const int* __restrict__ dst_q,
                              const int* __restrict__ rp_d, const int* __restrict__ rp_q,
                              int* __restrict__ cur_d, int* __restrict__ cur_q,
                              int* __restrict__ col_d, int* __restrict__ col_q) {
  int i = blockIdx.x * 256 + threadIdx.x;
  if (i < cEd) {
    int d = dst_d[i];
    int p = atomicAdd(&cur_d[d], 1);
    col_d[rp_d[d] + p] = src_d[i];
  } else {
    int j = i - cEd;
    int d = dst_q[j];
    int p = atomicAdd(&cur_q[d], 1);
    col_q[rp_q[d] + p] = src_q[j];
  }
}

// ---------------------------------------------------------------------------
// Merged GCN dense GEMM, XCD-swizzled on the data section.
// grid 544: data [0,512) swizzled (S=8), query [512,544).
// ---------------------------------------------------------------------------
template <int KD>
__global__ __launch_bounds__(256) void gmn_gemm_merged(
    const ushort* __restrict__ Xd, const ushort* __restrict__ Xq,
    const ushort* __restrict__ WT, const float* __restrict__ dinv_d,
    const float* __restrict__ dinv_q, ushort* __restrict__ H) {
  int blk = blockIdx.x;
  int tid = threadIdx.x;
  int wave = tid >> 6, lane = tid & 63;
  int col = lane & 15, quad = lane >> 4;
  bool isQ = blk >= 512;
  int node0;
  if (isQ) node0 = (blk - 512) * 64;
  else node0 = swz_g(blk) * 512 + (blk >> 6) * 64;
  int mloc = node0 + wave * 16;
  const ushort* X = isQ ? Xq : Xd;
  const float* dv = isQ ? dinv_q : dinv_d;
  size_t hbase = isQ ? (size_t)cNd : 0;
  floatx4 acc[8];
#pragma unroll
  for (int ct = 0; ct < 8; ++ct)
#pragma unroll
    for (int r = 0; r < 4; ++r) acc[ct][r] = 0.0f;
#pragma unroll
  for (int kc = 0; kc < KD / 32; ++kc) {
    bf16x8 a = *(const bf16x8*)(X + (size_t)(mloc + col) * KD + kc * 32 + quad * 8);
#pragma unroll
    for (int ct = 0; ct < 8; ++ct) {
      bf16x8 b = *(const bf16x8*)(WT + (size_t)(ct * 16 + col) * KD + kc * 32 + quad * 8);
      acc[ct] = __builtin_amdgcn_mfma_f32_16x16x32_bf16(a, b, acc[ct], 0, 0, 0);
    }
  }
  float sc[4];
#pragma unroll
  for (int r = 0; r < 4; ++r) sc[r] = dv[mloc + quad * 4 + r];
#pragma unroll
  for (int ct = 0; ct < 8; ++ct)
#pragma unroll
    for (int r = 0; r < 4; ++r)
      H[(hbase + mloc + quad * 4 + r) * 128 + ct * 16 + col] = f2bf(acc[ct][r] * sc[r]);
}

// ---------------------------------------------------------------------------
// Merged GCN aggregate, XCD-swizzled. grid 4352: data [0,4096) S=64,
// query [4096,4352) S=4. 8 nodes/block, 32 lanes/node.
// ---------------------------------------------------------------------------
__global__ __launch_bounds__(256) void gmn_gather_merged(
    const ushort* __restrict__ htmp, const int* __restrict__ rp_d,
    const int* __restrict__ cnt_d, const int* __restrict__ col_d,
    const float* __restrict__ dinv_d, const int* __restrict__ rp_q,
    const int* __restrict__ cnt_q, const int* __restrict__ col_q,
    const float* __restrict__ dinv_q, const float* __restrict__ bias,
    ushort* __restrict__ dbf, ushort* __restrict__ qbf) {
  int blk = blockIdx.x, tid = threadIdx.x;
  bool isQ = blk >= 4096;
  int node;
  if (isQ) {
    int j = blk - 4096;
    node = swz_g(j) * 32 + (j >> 6) * 8 + (tid >> 5);
  } else {
    node = swz_g(blk) * 512 + (blk >> 6) * 8 + (tid >> 5);
  }
  int l = tid & 31;
  const ushort* hs = htmp + (isQ ? (size_t)cNd * 128 : 0);
  const int* rp = isQ ? rp_q : rp_d;
  const int* cnt = isQ ? cnt_q : cnt_d;
  const int* col = isQ ? col_q : col_d;
  const float* dinv = isQ ? dinv_q : dinv_d;
  ushort* outp = isQ ? qbf : dbf;
  int c = cnt[node], s0 = rp[node];
  float dt = dinv[node];
  float4 acc = us4f4(*(const ushort4*)(hs + (size_t)node * 128 + l * 4));
  int cm = c < 32 ? c : 32;
  for (int j0 = 0; j0 < cm; j0 += 8) {
    int ss[8];
    ushort4 v[8];
#pragma unroll
    for (int t = 0; t < 8; ++t) {
      int jj = j0 + t;
      ss[t] = col[s0 + (jj < c ? jj : c - 1)];
    }
#pragma unroll
    for (int t = 0; t < 8; ++t)
      v[t] = *(const ushort4*)(hs + (size_t)ss[t] * 128 + l * 4);
#pragma unroll
    for (int t = 0; t < 8; ++t) {
      if (j0 + t < cm) {
        float4 f = us4f4(v[t]);
        acc.x += f.x; acc.y += f.y; acc.z += f.z; acc.w += f.w;
      }
    }
  }
  for (int j = 32; j < c; ++j) {
    int s = col[s0 + j];
    float4 f = us4f4(*(const ushort4*)(hs + (size_t)s * 128 + l * 4));
    acc.x += f.x; acc.y += f.y; acc.z += f.z; acc.w += f.w;
  }
  float4 bv = F4C(bias + l * 4);
  float4 r;
  r.x = fmaxf(acc.x * dt + bv.x, 0.0f);
  r.y = fmaxf(acc.y * dt + bv.y, 0.0f);
  r.z = fmaxf(acc.z * dt + bv.z, 0.0f);
  r.w = fmaxf(acc.w * dt + bv.w, 0.0f);
  *(ushort4*)(outp + (size_t)node * 128 + l * 4) = f4us4(r);
}

// ---------------------------------------------------------------------------
// Fused level prep (XCD-swizzled per section):
// grid 1792 = qw[0,1024) S=16 | logits[1024,1536) S=8 | ld[1536,1664) S=2
// | lq[1664,1792).
// ---------------------------------------------------------------------------
__global__ __launch_bounds__(256) void gmn_prep(
    const ushort* __restrict__ qbf, const ushort* __restrict__ dbf,
    const ushort* __restrict__ wnT, const ushort* __restrict__ vnbf,
    const float* __restrict__ Vn, ushort* __restrict__ qw,
    float* __restrict__ lgt, float* __restrict__ ldb, float* __restrict__ lqb) {
  __shared__ float sh_r[16 * 132];
  __shared__ float sh_v[16 * 132];
  int blk = blockIdx.x, tid = threadIdx.x;
  int wave = tid >> 6, lane = tid & 63;
  int col = lane & 15, quad = lane >> 4;

  if (blk < 1024) {  // qW[b,k] = q[b] @ Wn[k]
    int b = swz_g(blk), k = blk >> 6;
    int et0 = wave * 2;
    floatx4 acc[2][2];
#pragma unroll
    for (int qt = 0; qt < 2; ++qt)
#pragma unroll
      for (int ei = 0; ei < 2; ++ei)
#pragma unroll
        for (int r = 0; r < 4; ++r) acc[qt][ei][r] = 0.0f;
#pragma unroll
    for (int kc = 0; kc < 4; ++kc) {
      bf16x8 a0 = *(const bf16x8*)(qbf + (size_t)(b * 32 + col) * 128 + kc * 32 + quad * 8);
      bf16x8 a1 = *(const bf16x8*)(qbf + (size_t)(b * 32 + 16 + col) * 128 + kc * 32 + quad * 8);
#pragma unroll
      for (int ei = 0; ei < 2; ++ei) {
        bf16x8 bf = *(const bf16x8*)(wnT + (size_t)(k * 128 + (et0 + ei) * 16 + col) * 128 +
                                     kc * 32 + quad * 8);
        acc[0][ei] = __builtin_amdgcn_mfma_f32_16x16x32_bf16(a0, bf, acc[0][ei], 0, 0, 0);
        acc[1][ei] = __builtin_amdgcn_mfma_f32_16x16x32_bf16(a1, bf, acc[1][ei], 0, 0, 0);
      }
    }
#pragma unroll
    for (int qt = 0; qt < 2; ++qt)
#pragma unroll
      for (int ei = 0; ei < 2; ++ei)
#pragma unroll
        for (int r = 0; r < 4; ++r)
          qw[((size_t)(b * 16 + k) << 12) + (qt * 16 + quad * 4 + r) * 128 +
             (et0 + ei) * 16 + col] = f2bf(acc[qt][ei][r]);
  } else if (blk < 1536) {  // raw scaled logits
    int j = blk - 1024;
    int b = swz_g(j), nc = j >> 6;
    int n = nc * 64 + wave * 16 + col;
    floatx4 acc[2];
#pragma unroll
    for (int qt = 0; qt < 2; ++qt)
#pragma unroll
      for (int r = 0; r < 4; ++r) acc[qt][r] = 0.0f;
#pragma unroll
    for (int kc = 0; kc < 4; ++kc) {
      bf16x8 bf = *(const bf16x8*)(dbf + ((size_t)(b * 512 + n) << 7) + kc * 32 + quad * 8);
      bf16x8 a0 = *(const bf16x8*)(qbf + (size_t)(b * 32 + col) * 128 + kc * 32 + quad * 8);
      bf16x8 a1 = *(const bf16x8*)(qbf + (size_t)(b * 32 + 16 + col) * 128 + kc * 32 + quad * 8);
      acc[0] = __builtin_amdgcn_mfma_f32_16x16x32_bf16(a0, bf, acc[0], 0, 0, 0);
      acc[1] = __builtin_amdgcn_mfma_f32_16x16x32_bf16(a1, bf, acc[1], 0, 0, 0);
    }
    const float sc = 0.088388347648318440550f;  // 1/sqrt(128)
#pragma unroll
    for (int qt = 0; qt < 2; ++qt)
#pragma unroll
      for (int r = 0; r < 4; ++r)
        lgt[((size_t)(b * 32 + qt * 16 + quad * 4 + r) << 9) + n] = acc[qt][r] * sc;
  } else if (blk < 1664) {  // ld[b,k,n] = d · Vn[k][128:]
    int j = blk - 1536;
    int b = swz_g(j), half = j >> 6;
    bf16x8 bfr[4];
#pragma unroll
    for (int kc = 0; kc < 4; ++kc)
      bfr[kc] = *(const bf16x8*)(vnbf + col * 256 + 128 + kc * 32 + quad * 8);
#pragma unroll
    for (int i = 0; i < 4; ++i) {
      int mt = half * 16 + wave * 4 + i;
      floatx4 acc;
#pragma unroll
      for (int r = 0; r < 4; ++r) acc[r] = 0.0f;
#pragma unroll
      for (int kc = 0; kc < 4; ++kc) {
        bf16x8 a = *(const bf16x8*)(dbf + ((size_t)(b * 512 + mt * 16 + col) << 7) +
                                    kc * 32 + quad * 8);
        acc = __builtin_amdgcn_mfma_f32_16x16x32_bf16(a, bfr[kc], acc, 0, 0, 0);
      }
#pragma unroll
      for (int r = 0; r < 4; ++r)
        ldb[((size_t)(b * 16 + col) << 9) + mt * 16 + quad * 4 + r] = acc[r];
    }
  } else {  // lq rowdot
    int j = blk - 1664;
    int g0 = j * 16;
#pragma unroll
    for (int i = 0; i < 8; ++i) {
      int jj = tid + 256 * i;
      int a = jj >> 7, e = jj & 127;
      sh_r[a * 132 + e] = bf2f(qbf[(size_t)(g0 + a) * 128 + e]);
      sh_v[a * 132 + e] = Vn[a * 256 + e];
    }
    __syncthreads();
    int r = tid & 15, k = tid >> 4;
    float s = 0.0f;
#pragma unroll 8
    for (int e = 0; e < 128; ++e) s += sh_r[r * 132 + e] * sh_v[k * 132 + e];
    int g = g0 + r;
    int b = g >> 5, rr = g & 31;
    lqb[((b * 16 + k) << 5) + rr] = s;
  }
}

// ---------------------------------------------------------------------------
// MFMA NTN level kernel, split-k x2, XCD-swizzled. grid 1024, S=16:
// b = swz_g(blk); sub = blk>>6; kh = sub&1; nc = sub>>1.
// ---------------------------------------------------------------------------
__global__ __launch_bounds__(256, 4) void gmn_level_mfma(
    const ushort* __restrict__ qw, const ushort* __restrict__ dbf,
    const float* __restrict__ lqb, const float* __restrict__ ldb,
    const float* __restrict__ bn, const float* __restrict__ cw,
    const float* __restrict__ w_end, int o1, int o2, int do_facc,
    float* __restrict__ Ebuf, float* __restrict__ Fbuf) {
  __shared__ float s_ld[8 * 64];
  __shared__ float s_lq[8 * 32];
  int tid = threadIdx.x;
  int wave = tid >> 6, lane = tid & 63;
  int b = swz_g(blockIdx.x);
  int sub = blockIdx.x >> 6;
  int kh = sub & 1, nc = sub >> 1;
  int k0 = kh * 8;
  int col = lane & 15, quad = lane >> 4;
  int nn = wave * 16 + col;
  int n = nc * 64 + nn;

#pragma unroll
  for (int i = 0; i < 2; ++i) {
    int j = tid + 256 * i;
    int kk = j >> 6, nl = j & 63;
    s_ld[j] = ldb[((b * 16 + k0 + kk) << 9) + nc * 64 + nl];
  }
  {
    int kk = tid >> 5, qq = tid & 31;
    s_lq[tid] = lqb[(b * 16 + k0 + kk) * 32 + qq];
  }
  __syncthreads();

  float bnk[8], cwk[8], wkk[8];
#pragma unroll
  for (int kk = 0; kk < 8; ++kk) {
    bnk[kk] = bn[k0 + kk];
    cwk[kk] = cw[k0 + kk];
    float w = 0.0f;
    if (do_facc) {
      w = w_end[o1 + k0 + kk];
      if (o2 >= 0) w += w_end[o2 + k0 + kk];
    }
    wkk[kk] = w;
  }

  const ushort* dptr = dbf + (((size_t)(b * 512 + n)) << 7) + quad * 8;
  bf16x8 bfr[4];
#pragma unroll
  for (int kc = 0; kc < 4; ++kc) bfr[kc] = *(const bf16x8*)(dptr + kc * 32);

  const ushort* qwb = qw + ((size_t)b << 16) + (k0 << 12) + quad * 8;
  floatx4 eacc[2], facc[2];
#pragma unroll
  for (int t = 0; t < 2; ++t)
#pragma unroll
    for (int r = 0; r < 4; ++r) { eacc[t][r] = 0.0f; facc[t][r] = 0.0f; }

#pragma unroll 2
  for (int kk = 0; kk < 8; ++kk) {
    const ushort* qk = qwb + (kk << 12);
    floatx4 bil[2];
#pragma unroll
    for (int t = 0; t < 2; ++t)
#pragma unroll
      for (int r = 0; r < 4; ++r) bil[t][r] = 0.0f;
#pragma unroll
    for (int kc = 0; kc < 4; ++kc) {
      bf16x8 a0 = *(const bf16x8*)(qk + (col << 7) + kc * 32);
      bf16x8 a1 = *(const bf16x8*)(qk + ((col + 16) << 7) + kc * 32);
      bil[0] = __builtin_amdgcn_mfma_f32_16x16x32_bf16(a0, bfr[kc], bil[0], 0, 0, 0);
      bil[1] = __builtin_amdgcn_mfma_f32_16x16x32_bf16(a1, bfr[kc], bil[1], 0, 0, 0);
    }
    float ldv = s_ld[kk * 64 + nn] + bnk[kk];
#pragma unroll
    for (int t = 0; t < 2; ++t) {
#pragma unroll
      for (int r = 0; r < 4; ++r) {
        float lqv = s_lq[kk * 32 + t * 16 + quad * 4 + r];
        float sg = fsigmoid(bil[t][r] + lqv + ldv);
        eacc[t][r] += cwk[kk] * sg;
        facc[t][r] += wkk[kk] * sg;
      }
    }
  }

  float* Ep = Ebuf + (size_t)kh * cSZ;
  float* Fp = Fbuf + (size_t)kh * cSZ;
#pragma unroll
  for (int t = 0; t < 2; ++t) {
#pragma unroll
    for (int r = 0; r < 4; ++r) {
      size_t idx = ((size_t)(b * 32 + t * 16 + quad * 4 + r) << 9) + n;
      Ep[idx] = eacc[t][r];
      if (do_facc) Fp[idx] = facc[t][r];
    }
  }
}

// ---------------------------------------------------------------------------
// combine, XCD-swizzled. grid 2048 = 64 graphs x 32 q-rows (S=32):
// b = swz_g(blk); qrow = blk>>6.
// a = softmax_row(lgt); v = a*(E0+E1); f = a*(F0+F1);
// t = w*(do_sm ? softmax_row(v) : v) + f
// mode 0: accb=t | 1: accb+=t | 2: out = softmax_row(accb+t+be)
// ---------------------------------------------------------------------------
__global__ __launch_bounds__(256) void gmn_combine2(
    const float* __restrict__ lgt, const float* __restrict__ Ebuf,
    const float* __restrict__ Fbuf, float* __restrict__ accb,
    const float* __restrict__ w_end, const float* __restrict__ b_end,
    int widx, int do_sm, int hasF, int mode, float* __restrict__ out) {
  __shared__ float sh[8];
  int tid = threadIdx.x;
  int b = swz_g(blockIdx.x);
  int qrow = blockIdx.x >> 6;
  size_t base = (size_t)(b * 32 + qrow) * 512;
  size_t i0 = base + tid, i1 = i0 + 256;
  float w = w_end[widx];
  float l0 = lgt[i0], l1 = lgt[i1];
  float m = fmaxf(l0, l1);
#pragma unroll
  for (int o = 32; o; o >>= 1) m = fmaxf(m, __shfl_xor(m, o, 64));
  if ((tid & 63) == 0) sh[tid >> 6] = m;
  __syncthreads();
  m = fmaxf(fmaxf(sh[0], sh[1]), fmaxf(sh[2], sh[3]));
  float e0 = fexp(l0 - m), e1 = fexp(l1 - m);
  float s = e0 + e1;
#pragma unroll
  for (int o = 32; o; o >>= 1) s += __shfl_xor(s, o, 64);
  if ((tid & 63) == 0) sh[4 + (tid >> 6)] = s;
  __syncthreads();
  s = sh[4] + sh[5] + sh[6] + sh[7];
  float ainv = frcp(s);
  float a0 = e0 * ainv, a1 = e1 * ainv;
  __syncthreads();
  float v0 = a0 * (Ebuf[i0] + Ebuf[i0 + cSZ]);
  float v1 = a1 * (Ebuf[i1] + Ebuf[i1 + cSZ]);
  float f0 = 0.0f, f1 = 0.0f;
  if (hasF) {
    f0 = a0 * (Fbuf[i0] + Fbuf[i0 + cSZ]);
    f1 = a1 * (Fbuf[i1] + Fbuf[i1 + cSZ]);
  }
  if (do_sm) {
    float mm = fmaxf(v0, v1);
#pragma unroll
    for (int o = 32; o; o >>= 1) mm = fmaxf(mm, __shfl_xor(mm, o, 64));
    if ((tid & 63) == 0) sh[tid >> 6] = mm;
    __syncthreads();
    mm = fmaxf(fmaxf(sh[0], sh[1]), fmaxf(sh[2], sh[3]));
    float ee0 = fexp(v0 - mm), ee1 = fexp(v1 - mm);
    float ss = ee0 + ee1;
#pragma unroll
    for (int o = 32; o; o >>= 1) ss += __shfl_xor(ss, o, 64);
    if ((tid & 63) == 0) sh[4 + (tid >> 6)] = ss;
    __syncthreads();
    ss = sh[4] + sh[5] + sh[6] + sh[7];
    float inv = frcp(ss);
    v0 = ee0 * inv;
    v1 = ee1 * inv;
    __syncthreads();
  }
  float t0 = w * v0 + f0, t1 = w * v1 + f1;
  if (mode == 0) {
    accb[i0] = t0;
    accb[i1] = t1;
  } else if (mode == 1) {
    accb[i0] += t0;
    accb[i1] += t1;
  } else {
    float be = b_end[0];
    float z0 = accb[i0] + t0 + be, z1 = accb[i1] + t1 + be;
    float mm = fmaxf(z0, z1);
#pragma unroll
    for (int o = 32; o; o >>= 1) mm = fmaxf(mm, __shfl_xor(mm, o, 64));
    if ((tid & 63) == 0) sh[tid >> 6] = mm;
    __syncthreads();
    mm = fmaxf(fmaxf(sh[0], sh[1]), fmaxf(sh[2], sh[3]));
    float ee0 = fexp(z0 - mm), ee1 = fexp(z1 - mm);
    float ss = ee0 + ee1;
#pragma unroll
    for (int o = 32; o; o >>= 1) ss += __shfl_xor(ss, o, 64);
    if ((tid & 63) == 0) sh[4 + (tid >> 6)] = ss;
    __syncthreads();
    ss = sh[4] + sh[5] + sh[6] + sh[7];
    float inv = frcp(ss);
    out[i0] = ee0 * inv;
    out[i1] = ee1 * inv;
  }
}

// ---------------------------------------------------------------------------
// Host orchestration (R5 structure: 1 memset + 23 kernels)
// ---------------------------------------------------------------------------
extern "C" void kernel_launch(void* const* d_in, const int* in_sizes, int n_in,
                              void* d_out, int out_size, void* d_ws, size_t ws_size,
                              hipStream_t stream) {
  (void)in_sizes; (void)n_in; (void)out_size; (void)ws_size;
  const float* x_d = (const float*)d_in[0];
  const float* x_q = (const float*)d_in[1];
  const int* ei_d = (const int*)d_in[2];
  const int* ei_q = (const int*)d_in[3];
  const float* W1 = (const float*)d_in[6];
  const float* b1 = (const float*)d_in[7];
  const float* W2 = (const float*)d_in[8];
  const float* b2 = (const float*)d_in[9];
  const float* W3 = (const float*)d_in[10];
  const float* b3 = (const float*)d_in[11];
  const float* Wn[3] = {(const float*)d_in[12], (const float*)d_in[17], (const float*)d_in[22]};
  const float* Vn[3] = {(const float*)d_in[13], (const float*)d_in[18], (const float*)d_in[23]};
  const float* bn[3] = {(const float*)d_in[14], (const float*)d_in[19], (const float*)d_in[24]};
  const float* cw[3] = {(const float*)d_in[15], (const float*)d_in[20], (const float*)d_in[25]};
  const float* w_end = (const float*)d_in[27];
  const float* b_end = (const float*)d_in[28];
  float* out = (float*)d_out;

  char* wsp = (char*)d_ws;
  auto alloc = [&](size_t nbytes) {
    void* p = (void*)wsp;
    wsp += (nbytes + 255) & ~(size_t)255;
    return p;
  };
  int* cnt_d = (int*)alloc(cNd * 4);
  int* cnt_q = (int*)alloc(cNq * 4);
  int* cur_d = (int*)alloc(cNd * 4);
  int* cur_q = (int*)alloc(cNq * 4);
  float* dinv_d = (float*)alloc(cNd * 4);
  float* dinv_q = (float*)alloc(cNq * 4);
  int* rp_d = (int*)alloc(cNd * 4);
  int* rp_q = (int*)alloc(cNq * 4);
  int* col_d = (int*)alloc((size_t)cEd * 4);
  int* col_q = (int*)alloc((size_t)cEq * 4);
  int* bsum = (int*)alloc(64 * 4);
  ushort* xdbf = (ushort*)alloc((size_t)cNd * 64 * 2);
  ushort* xqbf = (ushort*)alloc((size_t)cNq * 64 * 2);
  ushort* w1T = (ushort*)alloc(128 * 64 * 2);
  ushort* w2T = (ushort*)alloc(128 * 128 * 2);
  ushort* w3T = (ushort*)alloc(128 * 128 * 2);
  ushort* wnT[3];
  for (int l = 0; l < 3; ++l) wnT[l] = (ushort*)alloc((size_t)16 * 128 * 128 * 2);
  ushort* vnbf[3];
  for (int l = 0; l < 3; ++l) vnbf[l] = (ushort*)alloc(16 * 256 * 2);
  ushort* htmp = (ushort*)alloc((size_t)(cNd + cNq) * 128 * 2);
  ushort* dbf = (ushort*)alloc((size_t)cNd * 128 * 2);
  ushort* qbf[3];
  for (int l = 0; l < 3; ++l) qbf[l] = (ushort*)alloc((size_t)cNq * 128 * 2);
  float* lgt = (float*)alloc(cSZ * 4);
  float* Ebuf = (float*)alloc(cSZ * 2 * 4);
  float* Fbuf = (float*)alloc(cSZ * 2 * 4);
  float* accb = (float*)alloc(cSZ * 4);
  float* lqb = (float*)alloc((size_t)cB * 16 * 32 * 4);
  float* ldb = (float*)alloc((size_t)cB * 16 * 512 * 4);
  ushort* qwbuf = (ushort*)alloc((size_t)cB * 16 * 32 * 128 * 2);

  const int* src_d = ei_d;
  const int* dst_d = ei_d + cEd;
  const int* src_q = ei_q;
  const int* dst_q = ei_q + cEq;

  hipMemsetAsync(cnt_d, 0, (size_t)2 * (cNd + cNq) * 4, stream);

  // --- conversions ---
  gmn_cvt_all<<<2188, 256, 0, stream>>>(x_d, x_q, Vn[0], Vn[1], Vn[2], xdbf, xqbf,
                                        vnbf[0], vnbf[1], vnbf[2]);
  gmn_t2bf_all<<<808, 256, 0, stream>>>(W1, W2, W3, Wn[0], Wn[1], Wn[2], w1T, w2T, w3T,
                                        wnT[0], wnT[1], wnT[2]);

  // --- CSR ---
  gmn_count_both<<<(cEd + cEq) / 256, 256, 0, stream>>>(dst_d, dst_q, cnt_d, cnt_q);
  gmn_scan_local_both<<<34, 1024, 0, stream>>>(cnt_d, cnt_q, rp_d, rp_q, bsum);
  gmn_scan_off_both<<<1, 64, 0, stream>>>(bsum);
  gmn_scan_add_both<<<34, 1024, 0, stream>>>(rp_d, rp_q, bsum);
  gmn_dinv_both<<<(cNd + cNq) / 256, 256, 0, stream>>>(cnt_d, cnt_q, dinv_d, dinv_q);
  gmn_fill_both<<<(cEd + cEq) / 256, 256, 0, stream>>>(src_d, dst_d, src_q, dst_q, rp_d,
                                                       rp_q, cur_d, cur_q, col_d, col_q);

  const ushort* wT[3] = {w1T, w2T, w3T};
  const float* bias[3] = {b1, b2, b3};
  const int o1s[3] = {0, 19, 3};
  const int o2s[3] = {-1, -1, 35};
  const int dofac[3] = {0, 1, 1};
  const int dosms[3] = {1, 0, 1};
  const int modes[3] = {0, 1, 2};

  for (int l = 0; l < 3; ++l) {
    if (l == 0)
      gmn_gemm_merged<64><<<(cNd + cNq) / 64, 256, 0, stream>>>(xdbf, xqbf, w1T, dinv_d,
                                                                dinv_q, htmp);
    else
      gmn_gemm_merged<128><<<(cNd + cNq) / 64, 256, 0, stream>>>(dbf, qbf[l - 1], wT[l],
                                                                 dinv_d, dinv_q, htmp);
    gmn_gather_merged<<<(cNd + cNq) / 8, 256, 0, stream>>>(htmp, rp_d, cnt_d, col_d,
                                                           dinv_d, rp_q, cnt_q, col_q,
                                                           dinv_q, bias[l], dbf, qbf[l]);
    gmn_prep<<<1792, 256, 0, stream>>>(qbf[l], dbf, wnT[l], vnbf[l], Vn[l], qwbuf, lgt,
                                       ldb, lqb);
    gmn_level_mfma<<<1024, 256, 0, stream>>>(qwbuf, dbf, lqb, ldb, bn[l], cw[l],
                                             w_end, o1s[l], o2s[l], dofac[l],
                                             Ebuf, Fbuf);
    gmn_combine2<<<2048, 256, 0, stream>>>(lgt, Ebuf, Fbuf, accb, w_end, b_end, l,
                                           dosms[l], dofac[l], modes[l], out);
  }
}

// Round 8
// 354.165 us; speedup vs baseline: 1.2514x; 1.1246x over previous
//
#include <hip/hip_runtime.h>
#include <math.h>

// ---------------------------------------------------------------------------
// Problem constants (fixed production sizes from the reference)
// ---------------------------------------------------------------------------
namespace {
constexpr int cB  = 64;
constexpr int cNQ = 32;
constexpr int cND = 512;
constexpr int cNd = cB * cND;   // 32768
constexpr int cNq = cB * cNQ;   // 2048
constexpr int cEd = cNd * 8;    // 262144
constexpr int cEq = cNq * 8;    // 16384
constexpr int LD_STRIDE = 516;  // s_ld [16][516] pad -> 2-way bank max
}

#define F4C(p) (*(const float4*)(p))
#define F4W(p) (*(float4*)(p))

typedef __attribute__((ext_vector_type(8))) __bf16 bf16x8;
typedef __attribute__((ext_vector_type(4))) float floatx4;

__device__ __forceinline__ ushort f2bf(float f) {
  union { float f; unsigned u; } v;
  v.f = f;
  unsigned u = v.u;
  return (ushort)((u + 0x7fffu + ((u >> 16) & 1u)) >> 16);
}
__device__ __forceinline__ float bf2f(ushort u) {
  union { unsigned u; float f; } v;
  v.u = ((unsigned)u) << 16;
  return v.f;
}
__device__ __forceinline__ float4 us4f4(ushort4 u) {
  return make_float4(bf2f(u.x), bf2f(u.y), bf2f(u.z), bf2f(u.w));
}
__device__ __forceinline__ ushort4 f4us4(float4 f) {
  ushort4 o;
  o.x = f2bf(f.x); o.y = f2bf(f.y); o.z = f2bf(f.z); o.w = f2bf(f.w);
  return o;
}
__device__ __forceinline__ float fexp2(float x) {
#if __has_builtin(__builtin_amdgcn_exp2f)
  return __builtin_amdgcn_exp2f(x);
#else
  return exp2f(x);
#endif
}
__device__ __forceinline__ float frcp(float x) {
#if __has_builtin(__builtin_amdgcn_rcpf)
  return __builtin_amdgcn_rcpf(x);
#else
  return 1.0f / x;
#endif
}
__device__ __forceinline__ float fsigmoid(float z) {
  return frcp(1.0f + fexp2(z * -1.4426950408889634f));
}
__device__ __forceinline__ float fexp(float x) { return fexp2(x * 1.4426950408889634f); }

// XCD-affinity swizzle (blockIdx%8 -> XCD round-robin heuristic)
__device__ __forceinline__ int swz_g(int j) { return (((j >> 3) & 7) << 3) | (j & 7); }

// ---------------------------------------------------------------------------
// Fused conversions (grid 2188)
// ---------------------------------------------------------------------------
__global__ void gmn_cvt_all(const float* __restrict__ xd, const float* __restrict__ xq,
                            const float* __restrict__ v0, const float* __restrict__ v1,
                            const float* __restrict__ v2, ushort* __restrict__ oxd,
                            ushort* __restrict__ oxq, ushort* __restrict__ ov0,
                            ushort* __restrict__ ov1, ushort* __restrict__ ov2) {
  int blk = blockIdx.x, tid = threadIdx.x;
  const float* src;
  ushort* dst;
  int i;
  if (blk < 2048) { src = xd; dst = oxd; i = blk * 256 + tid; }
  else if (blk < 2176) { src = xq; dst = oxq; i = (blk - 2048) * 256 + tid; }
  else if (blk < 2180) { src = v0; dst = ov0; i = (blk - 2176) * 256 + tid; }
  else if (blk < 2184) { src = v1; dst = ov1; i = (blk - 2180) * 256 + tid; }
  else { src = v2; dst = ov2; i = (blk - 2184) * 256 + tid; }
  *(ushort4*)(dst + (size_t)i * 4) = f4us4(F4C(src + (size_t)i * 4));
}

// ---------------------------------------------------------------------------
// Fused transpose+convert weights (grid 808)
// ---------------------------------------------------------------------------
__global__ __launch_bounds__(256) void gmn_t2bf_all(
    const float* __restrict__ W1, const float* __restrict__ W2,
    const float* __restrict__ W3, const float* __restrict__ Wn0,
    const float* __restrict__ Wn1, const float* __restrict__ Wn2,
    ushort* __restrict__ o1, ushort* __restrict__ o2, ushort* __restrict__ o3,
    ushort* __restrict__ on0, ushort* __restrict__ on1, ushort* __restrict__ on2) {
  __shared__ float tile[32][33];
  int blk = blockIdx.x;
  const float* in;
  ushort* out;
  int R, C, bt, t;
  if (blk < 8)        { in = W1;  out = o1;  R = 64;  C = 128; bt = 0; t = blk; }
  else if (blk < 24)  { in = W2;  out = o2;  R = 128; C = 128; bt = 0; t = blk - 8; }
  else if (blk < 40)  { in = W3;  out = o3;  R = 128; C = 128; bt = 0; t = blk - 24; }
  else if (blk < 296) { in = Wn0; out = on0; R = 128; C = 128; bt = (blk - 40) >> 4;  t = (blk - 40) & 15; }
  else if (blk < 552) { in = Wn1; out = on1; R = 128; C = 128; bt = (blk - 296) >> 4; t = (blk - 296) & 15; }
  else                { in = Wn2; out = on2; R = 128; C = 128; bt = (blk - 552) >> 4; t = (blk - 552) & 15; }
  int tilesC = C >> 5;
  int tr = t / tilesC, tc = t - tr * tilesC;
  int tx = threadIdx.x & 31, ty = threadIdx.x >> 5;
  const float* ib = in + (size_t)bt * R * C;
  ushort* ob = out + (size_t)bt * R * C;
#pragma unroll
  for (int i = 0; i < 4; ++i)
    tile[ty + i * 8][tx] = ib[(tr * 32 + ty + i * 8) * C + tc * 32 + tx];
  __syncthreads();
#pragma unroll
  for (int i = 0; i < 4; ++i)
    ob[(size_t)(tc * 32 + ty + i * 8) * R + tr * 32 + tx] = f2bf(tile[tx][ty + i * 8]);
}

// ---------------------------------------------------------------------------
// CSR construction (merged d+q)
// ---------------------------------------------------------------------------
__global__ void gmn_count_both(const int* __restrict__ dst_d, const int* __restrict__ dst_q,
                               int* __restrict__ cnt_d, int* __restrict__ cnt_q) {
  int i = blockIdx.x * 256 + threadIdx.x;
  if (i < cEd) atomicAdd(&cnt_d[dst_d[i]], 1);
  else atomicAdd(&cnt_q[dst_q[i - cEd]], 1);
}

__global__ __launch_bounds__(1024) void gmn_scan_local_both(
    const int* __restrict__ cnt_d, const int* __restrict__ cnt_q,
    int* __restrict__ rp_d, int* __restrict__ rp_q, int* __restrict__ bsum) {
  __shared__ int sh[1024];
  int blk = blockIdx.x, tid = threadIdx.x;
  bool isQ = blk >= 32;
  const int* cnt = isQ ? cnt_q : cnt_d;
  int* rp = isQ ? rp_q : rp_d;
  int base = (isQ ? blk - 32 : blk) * 1024;
  int v = cnt[base + tid];
  sh[tid] = v;
  __syncthreads();
  for (int off = 1; off < 1024; off <<= 1) {
    int t = (tid >= off) ? sh[tid - off] : 0;
    __syncthreads();
    sh[tid] += t;
    __syncthreads();
  }
  rp[base + tid] = sh[tid] - v;  // exclusive
  if (tid == 1023) bsum[blk] = sh[1023];
}

__global__ void gmn_scan_off_both(int* __restrict__ bsum) {
  int l = threadIdx.x;
  bool valid = l < 34;
  int v = valid ? bsum[l] : 0;
  int orig = v;
#pragma unroll
  for (int off = 1; off < 32; off <<= 1) {
    int t = __shfl_up(v, off, 32);
    if ((l & 31) >= off) v += t;
  }
  if (valid) bsum[l] = v - orig;  // exclusive within each 32-group
}

__global__ __launch_bounds__(1024) void gmn_scan_add_both(int* __restrict__ rp_d,
                                                          int* __restrict__ rp_q,
                                                          const int* __restrict__ bsum) {
  int blk = blockIdx.x, tid = threadIdx.x;
  if (blk < 32) rp_d[blk * 1024 + tid] += bsum[blk];
  else rp_q[(blk - 32) * 1024 + tid] += bsum[blk];
}

__global__ void gmn_dinv_both(const int* __restrict__ cnt_d, const int* __restrict__ cnt_q,
                              float* __restrict__ dinv_d, float* __restrict__ dinv_q) {
  int i = blockIdx.x * 256 + threadIdx.x;
  if (i < cNd) dinv_d[i] = 1.0f / sqrtf((float)(cnt_d[i] + 1));
  else { int j = i - cNd; dinv_q[j] = 1.0f / sqrtf((float)(cnt_q[j] + 1)); }
}

__global__ void gmn_fill_both(const int* __restrict__ src_d, const int* __restrict__ dst_d,
                              const int* __restrict__ src_q, const int* __restrict__ dst_q,
                              const int* __restrict__ rp_d, const int* __restrict__ rp_q,
                              int* __restrict__ cur_d, int* __restrict__ cur_q,
                              int* __restrict__ col_d, int* __restrict__ col_q) {
  int i = blockIdx.x * 256 + threadIdx.x;
  if (i < cEd) {
    int d = dst_d[i];
    int p = atomicAdd(&cur_d[d], 1);
    col_d[rp_d[d] + p] = src_d[i];
  } else {
    int j = i - cEd;
    int d = dst_q[j];
    int p = atomicAdd(&cur_q[d], 1);
    col_q[rp_q[d] + p] = src_q[j];
  }
}

// ---------------------------------------------------------------------------
// Merged GCN dense GEMM (XCD-swizzled data). grid 544.
// ---------------------------------------------------------------------------
template <int KD>
__global__ __launch_bounds__(256) void gmn_gemm_merged(
    const ushort* __restrict__ Xd, const ushort* __restrict__ Xq,
    const ushort* __restrict__ WT, const float* __restrict__ dinv_d,
    const float* __restrict__ dinv_q, ushort* __restrict__ H) {
  int blk = blockIdx.x;
  int tid = threadIdx.x;
  int wave = tid >> 6, lane = tid & 63;
  int col = lane & 15, quad = lane >> 4;
  bool isQ = blk >= 512;
  int node0;
  if (isQ) node0 = (blk - 512) * 64;
  else node0 = swz_g(blk) * 512 + (blk >> 6) * 64;
  int mloc = node0 + wave * 16;
  const ushort* X = isQ ? Xq : Xd;
  const float* dv = isQ ? dinv_q : dinv_d;
  size_t hbase = isQ ? (size_t)cNd : 0;
  floatx4 acc[8];
#pragma unroll
  for (int ct = 0; ct < 8; ++ct)
#pragma unroll
    for (int r = 0; r < 4; ++r) acc[ct][r] = 0.0f;
#pragma unroll
  for (int kc = 0; kc < KD / 32; ++kc) {
    bf16x8 a = *(const bf16x8*)(X + (size_t)(mloc + col) * KD + kc * 32 + quad * 8);
#pragma unroll
    for (int ct = 0; ct < 8; ++ct) {
      bf16x8 b = *(const bf16x8*)(WT + (size_t)(ct * 16 + col) * KD + kc * 32 + quad * 8);
      acc[ct] = __builtin_amdgcn_mfma_f32_16x16x32_bf16(a, b, acc[ct], 0, 0, 0);
    }
  }
  float sc[4];
#pragma unroll
  for (int r = 0; r < 4; ++r) sc[r] = dv[mloc + quad * 4 + r];
#pragma unroll
  for (int ct = 0; ct < 8; ++ct)
#pragma unroll
    for (int r = 0; r < 4; ++r)
      H[(hbase + mloc + quad * 4 + r) * 128 + ct * 16 + col] = f2bf(acc[ct][r] * sc[r]);
}

// ---------------------------------------------------------------------------
// Merged GCN aggregate (XCD-swizzled). grid 4352.
// ---------------------------------------------------------------------------
__global__ __launch_bounds__(256) void gmn_gather_merged(
    const ushort* __restrict__ htmp, const int* __restrict__ rp_d,
    const int* __restrict__ cnt_d, const int* __restrict__ col_d,
    const float* __restrict__ dinv_d, const int* __restrict__ rp_q,
    const int* __restrict__ cnt_q, const int* __restrict__ col_q,
    const float* __restrict__ dinv_q, const float* __restrict__ bias,
    ushort* __restrict__ dbf, ushort* __restrict__ qbf) {
  int blk = blockIdx.x, tid = threadIdx.x;
  bool isQ = blk >= 4096;
  int node;
  if (isQ) {
    int j = blk - 4096;
    node = swz_g(j) * 32 + (j >> 6) * 8 + (tid >> 5);
  } else {
    node = swz_g(blk) * 512 + (blk >> 6) * 8 + (tid >> 5);
  }
  int l = tid & 31;
  const ushort* hs = htmp + (isQ ? (size_t)cNd * 128 : 0);
  const int* rp = isQ ? rp_q : rp_d;
  const int* cnt = isQ ? cnt_q : cnt_d;
  const int* col = isQ ? col_q : col_d;
  const float* dinv = isQ ? dinv_q : dinv_d;
  ushort* outp = isQ ? qbf : dbf;
  int c = cnt[node], s0 = rp[node];
  float dt = dinv[node];
  float4 acc = us4f4(*(const ushort4*)(hs + (size_t)node * 128 + l * 4));
  int cm = c < 32 ? c : 32;
  for (int j0 = 0; j0 < cm; j0 += 8) {
    int ss[8];
    ushort4 v[8];
#pragma unroll
    for (int t = 0; t < 8; ++t) {
      int jj = j0 + t;
      ss[t] = col[s0 + (jj < c ? jj : c - 1)];
    }
#pragma unroll
    for (int t = 0; t < 8; ++t)
      v[t] = *(const ushort4*)(hs + (size_t)ss[t] * 128 + l * 4);
#pragma unroll
    for (int t = 0; t < 8; ++t) {
      if (j0 + t < cm) {
        float4 f = us4f4(v[t]);
        acc.x += f.x; acc.y += f.y; acc.z += f.z; acc.w += f.w;
      }
    }
  }
  for (int j = 32; j < c; ++j) {
    int s = col[s0 + j];
    float4 f = us4f4(*(const ushort4*)(hs + (size_t)s * 128 + l * 4));
    acc.x += f.x; acc.y += f.y; acc.z += f.z; acc.w += f.w;
  }
  float4 bv = F4C(bias + l * 4);
  float4 r;
  r.x = fmaxf(acc.x * dt + bv.x, 0.0f);
  r.y = fmaxf(acc.y * dt + bv.y, 0.0f);
  r.z = fmaxf(acc.z * dt + bv.z, 0.0f);
  r.w = fmaxf(acc.w * dt + bv.w, 0.0f);
  *(ushort4*)(outp + (size_t)node * 128 + l * 4) = f4us4(r);
}

// ---------------------------------------------------------------------------
// qW prep (XCD-swizzled): qW[b,k] = q[b] @ Wn[k]. grid 1024.
// ---------------------------------------------------------------------------
__global__ __launch_bounds__(256) void gmn_qw(const ushort* __restrict__ qbf,
                                              const ushort* __restrict__ wnT,
                                              ushort* __restrict__ qw) {
  int blk = blockIdx.x, tid = threadIdx.x;
  int wave = tid >> 6, lane = tid & 63;
  int col = lane & 15, quad = lane >> 4;
  int b = swz_g(blk), k = blk >> 6;
  int et0 = wave * 2;
  floatx4 acc[2][2];
#pragma unroll
  for (int qt = 0; qt < 2; ++qt)
#pragma unroll
    for (int ei = 0; ei < 2; ++ei)
#pragma unroll
      for (int r = 0; r < 4; ++r) acc[qt][ei][r] = 0.0f;
#pragma unroll
  for (int kc = 0; kc < 4; ++kc) {
    bf16x8 a0 = *(const bf16x8*)(qbf + (size_t)(b * 32 + col) * 128 + kc * 32 + quad * 8);
    bf16x8 a1 = *(const bf16x8*)(qbf + (size_t)(b * 32 + 16 + col) * 128 + kc * 32 + quad * 8);
#pragma unroll
    for (int ei = 0; ei < 2; ++ei) {
      bf16x8 bf = *(const bf16x8*)(wnT + (size_t)(k * 128 + (et0 + ei) * 16 + col) * 128 +
                                   kc * 32 + quad * 8);
      acc[0][ei] = __builtin_amdgcn_mfma_f32_16x16x32_bf16(a0, bf, acc[0][ei], 0, 0, 0);
      acc[1][ei] = __builtin_amdgcn_mfma_f32_16x16x32_bf16(a1, bf, acc[1][ei], 0, 0, 0);
    }
  }
#pragma unroll
  for (int qt = 0; qt < 2; ++qt)
#pragma unroll
    for (int ei = 0; ei < 2; ++ei)
#pragma unroll
      for (int r = 0; r < 4; ++r)
        qw[((size_t)(b * 16 + k) << 12) + (qt * 16 + quad * 4 + r) * 128 +
           (et0 + ei) * 16 + col] = f2bf(acc[qt][ei][r]);
}

// ---------------------------------------------------------------------------
// Row-complete fused NTN level kernel.
// grid 128: blk -> b = swz_g(blk&63), qh = blk>>6 (16 q-rows).
// 512 threads = 8 waves; wave owns 64 n (4 subtiles of 16).
// Does: att logits (MFMA) -> in-block att softmax -> ld/lq (MFMA, LDS) ->
// 16-k bil loop (MFMA) + sigmoid sums -> optional v-softmax -> accb/out.
// ---------------------------------------------------------------------------
__global__ __launch_bounds__(512, 2) void gmn_level_fused(
    const ushort* __restrict__ qbf, const ushort* __restrict__ dbf,
    const ushort* __restrict__ qw, const ushort* __restrict__ vnbf,
    const float* __restrict__ bn, const float* __restrict__ cw,
    const float* __restrict__ w_end, const float* __restrict__ b_end,
    int o1, int o2, int hasF, int do_sm, int mode, int widx,
    float* __restrict__ accb, float* __restrict__ out) {
  __shared__ float s_ld[16 * LD_STRIDE];  // [k][n] 33 KB
  __shared__ float s_lq[16 * 16];         // [k][q]
  __shared__ float s_red[16 * 8];         // [q][wave]
  int tid = threadIdx.x;
  int wave = tid >> 6, lane = tid & 63;
  int col = lane & 15, quad = lane >> 4;
  int b = swz_g(blockIdx.x & 63);
  int qh = blockIdx.x >> 6;
  int n0 = wave * 64;  // wave's n-tile base

  // --- load fragments ---
  // d rows (serve as B for q·d^T and bil, and as A for d@Vn2^T)
  bf16x8 bfr[4][4];  // [subtile][kc]
#pragma unroll
  for (int s = 0; s < 4; ++s)
#pragma unroll
    for (int kc = 0; kc < 4; ++kc)
      bfr[s][kc] = *(const bf16x8*)(dbf + ((size_t)(b * 512 + n0 + s * 16 + col) << 7) +
                                    kc * 32 + quad * 8);
  // q rows (A for q·d^T and q@Vn1^T)
  bf16x8 aq[4];
#pragma unroll
  for (int kc = 0; kc < 4; ++kc)
    aq[kc] = *(const bf16x8*)(qbf + (size_t)(b * 32 + qh * 16 + col) * 128 +
                              kc * 32 + quad * 8);

  // --- att logits: C[q][n] ---
  floatx4 att[4];
#pragma unroll
  for (int s = 0; s < 4; ++s)
#pragma unroll
    for (int r = 0; r < 4; ++r) att[s][r] = 0.0f;
#pragma unroll
  for (int kc = 0; kc < 4; ++kc)
#pragma unroll
    for (int s = 0; s < 4; ++s)
      att[s] = __builtin_amdgcn_mfma_f32_16x16x32_bf16(aq[kc], bfr[s][kc], att[s], 0, 0, 0);
  const float sc = 0.088388347648318440550f;  // 1/sqrt(128)
#pragma unroll
  for (int s = 0; s < 4; ++s)
#pragma unroll
    for (int r = 0; r < 4; ++r) att[s][r] *= sc;

  // --- ld = d @ Vn2^T: C[n][k'] -> LDS transpose ---
  {
    bf16x8 vn2[4];
#pragma unroll
    for (int kc = 0; kc < 4; ++kc)
      vn2[kc] = *(const bf16x8*)(vnbf + col * 256 + 128 + kc * 32 + quad * 8);
#pragma unroll
    for (int s = 0; s < 4; ++s) {
      floatx4 lda;
#pragma unroll
      for (int r = 0; r < 4; ++r) lda[r] = 0.0f;
#pragma unroll
      for (int kc = 0; kc < 4; ++kc)
        lda = __builtin_amdgcn_mfma_f32_16x16x32_bf16(bfr[s][kc], vn2[kc], lda, 0, 0, 0);
#pragma unroll
      for (int r = 0; r < 4; ++r)
        s_ld[col * LD_STRIDE + n0 + s * 16 + quad * 4 + r] = lda[r];
    }
  }
  // --- lq = q @ Vn1^T: C[q][k'] (wave 0 only) ---
  if (wave == 0) {
    bf16x8 vn1[4];
#pragma unroll
    for (int kc = 0; kc < 4; ++kc)
      vn1[kc] = *(const bf16x8*)(vnbf + col * 256 + kc * 32 + quad * 8);
    floatx4 lqa;
#pragma unroll
    for (int r = 0; r < 4; ++r) lqa[r] = 0.0f;
#pragma unroll
    for (int kc = 0; kc < 4; ++kc)
      lqa = __builtin_amdgcn_mfma_f32_16x16x32_bf16(aq[kc], vn1[kc], lqa, 0, 0, 0);
#pragma unroll
    for (int r = 0; r < 4; ++r) s_lq[col * 16 + quad * 4 + r] = lqa[r];
  }
  __syncthreads();

  // --- att softmax over n=512 (rows q=quad*4+r) ---
  float red[4], M[4];
  // max
#pragma unroll
  for (int r = 0; r < 4; ++r) {
    float m = fmaxf(fmaxf(att[0][r], att[1][r]), fmaxf(att[2][r], att[3][r]));
#pragma unroll
    for (int o = 1; o < 16; o <<= 1) m = fmaxf(m, __shfl_xor(m, o, 64));
    red[r] = m;
  }
  if (col == 0)
#pragma unroll
    for (int r = 0; r < 4; ++r) s_red[(quad * 4 + r) * 8 + wave] = red[r];
  __syncthreads();
#pragma unroll
  for (int r = 0; r < 4; ++r) {
    float m = s_red[(quad * 4 + r) * 8];
#pragma unroll
    for (int w = 1; w < 8; ++w) m = fmaxf(m, s_red[(quad * 4 + r) * 8 + w]);
    M[r] = m;
  }
  __syncthreads();
  // exp + sum
#pragma unroll
  for (int s = 0; s < 4; ++s)
#pragma unroll
    for (int r = 0; r < 4; ++r) att[s][r] = fexp(att[s][r] - M[r]);
#pragma unroll
  for (int r = 0; r < 4; ++r) {
    float m = att[0][r] + att[1][r] + att[2][r] + att[3][r];
#pragma unroll
    for (int o = 1; o < 16; o <<= 1) m += __shfl_xor(m, o, 64);
    red[r] = m;
  }
  if (col == 0)
#pragma unroll
    for (int r = 0; r < 4; ++r) s_red[(quad * 4 + r) * 8 + wave] = red[r];
  __syncthreads();
#pragma unroll
  for (int r = 0; r < 4; ++r) {
    float m = s_red[(quad * 4 + r) * 8];
#pragma unroll
    for (int w = 1; w < 8; ++w) m += s_red[(quad * 4 + r) * 8 + w];
    M[r] = frcp(m);
  }
  __syncthreads();
#pragma unroll
  for (int s = 0; s < 4; ++s)
#pragma unroll
    for (int r = 0; r < 4; ++r) att[s][r] *= M[r];

  // --- 16-k bil loop ---
  floatx4 eacc[4], facc[4];
#pragma unroll
  for (int s = 0; s < 4; ++s)
#pragma unroll
    for (int r = 0; r < 4; ++r) { eacc[s][r] = 0.0f; facc[s][r] = 0.0f; }

#pragma unroll 4
  for (int k = 0; k < 16; ++k) {
    const ushort* qk = qw + ((size_t)(b * 16 + k) << 12) + (qh * 16 + col) * 128 + quad * 8;
    bf16x8 a0 = *(const bf16x8*)(qk);
    bf16x8 a1 = *(const bf16x8*)(qk + 32);
    bf16x8 a2 = *(const bf16x8*)(qk + 64);
    bf16x8 a3 = *(const bf16x8*)(qk + 96);
    floatx4 bil[4];
#pragma unroll
    for (int s = 0; s < 4; ++s) {
#pragma unroll
      for (int r = 0; r < 4; ++r) bil[s][r] = 0.0f;
      bil[s] = __builtin_amdgcn_mfma_f32_16x16x32_bf16(a0, bfr[s][0], bil[s], 0, 0, 0);
      bil[s] = __builtin_amdgcn_mfma_f32_16x16x32_bf16(a1, bfr[s][1], bil[s], 0, 0, 0);
      bil[s] = __builtin_amdgcn_mfma_f32_16x16x32_bf16(a2, bfr[s][2], bil[s], 0, 0, 0);
      bil[s] = __builtin_amdgcn_mfma_f32_16x16x32_bf16(a3, bfr[s][3], bil[s], 0, 0, 0);
    }
    float bnk = bn[k], cwk = cw[k];
    float wkk = 0.0f;
    if (hasF) {
      wkk = w_end[o1 + k];
      if (o2 >= 0) wkk += w_end[o2 + k];
    }
    float lqv[4];
#pragma unroll
    for (int r = 0; r < 4; ++r) lqv[r] = s_lq[k * 16 + quad * 4 + r] + bnk;
#pragma unroll
    for (int s = 0; s < 4; ++s) {
      float ldv = s_ld[k * LD_STRIDE + n0 + s * 16 + col];
#pragma unroll
      for (int r = 0; r < 4; ++r) {
        float sg = fsigmoid(bil[s][r] + lqv[r] + ldv);
        eacc[s][r] += cwk * sg;
        facc[s][r] += wkk * sg;
      }
    }
  }

  // --- epilogue: v = att*eacc, f = att*facc ---
#pragma unroll
  for (int s = 0; s < 4; ++s)
#pragma unroll
    for (int r = 0; r < 4; ++r) {
      eacc[s][r] *= att[s][r];
      facc[s][r] *= att[s][r];
    }
  if (do_sm) {  // row softmax of v
#pragma unroll
    for (int r = 0; r < 4; ++r) {
      float m = fmaxf(fmaxf(eacc[0][r], eacc[1][r]), fmaxf(eacc[2][r], eacc[3][r]));
#pragma unroll
      for (int o = 1; o < 16; o <<= 1) m = fmaxf(m, __shfl_xor(m, o, 64));
      red[r] = m;
    }
    if (col == 0)
#pragma unroll
      for (int r = 0; r < 4; ++r) s_red[(quad * 4 + r) * 8 + wave] = red[r];
    __syncthreads();
#pragma unroll
    for (int r = 0; r < 4; ++r) {
      float m = s_red[(quad * 4 + r) * 8];
#pragma unroll
      for (int w = 1; w < 8; ++w) m = fmaxf(m, s_red[(quad * 4 + r) * 8 + w]);
      M[r] = m;
    }
    __syncthreads();
#pragma unroll
    for (int s = 0; s < 4; ++s)
#pragma unroll
      for (int r = 0; r < 4; ++r) eacc[s][r] = fexp(eacc[s][r] - M[r]);
#pragma unroll
    for (int r = 0; r < 4; ++r) {
      float m = eacc[0][r] + eacc[1][r] + eacc[2][r] + eacc[3][r];
#pragma unroll
      for (int o = 1; o < 16; o <<= 1) m += __shfl_xor(m, o, 64);
      red[r] = m;
    }
    if (col == 0)
#pragma unroll
      for (int r = 0; r < 4; ++r) s_red[(quad * 4 + r) * 8 + wave] = red[r];
    __syncthreads();
#pragma unroll
    for (int r = 0; r < 4; ++r) {
      float m = s_red[(quad * 4 + r) * 8];
#pragma unroll
      for (int w = 1; w < 8; ++w) m += s_red[(quad * 4 + r) * 8 + w];
      M[r] = frcp(m);
    }
    __syncthreads();
#pragma unroll
    for (int s = 0; s < 4; ++s)
#pragma unroll
      for (int r = 0; r < 4; ++r) eacc[s][r] *= M[r];
  }
  float w = w_end[widx];
  // t = w*v + f  (into eacc)
#pragma unroll
  for (int s = 0; s < 4; ++s)
#pragma unroll
    for (int r = 0; r < 4; ++r) eacc[s][r] = w * eacc[s][r] + (hasF ? facc[s][r] : 0.0f);

  if (mode == 0) {
#pragma unroll
    for (int s = 0; s < 4; ++s)
#pragma unroll
      for (int r = 0; r < 4; ++r)
        accb[((size_t)(b * 32 + qh * 16 + quad * 4 + r) << 9) + n0 + s * 16 + col] =
            eacc[s][r];
  } else if (mode == 1) {
#pragma unroll
    for (int s = 0; s < 4; ++s)
#pragma unroll
      for (int r = 0; r < 4; ++r)
        accb[((size_t)(b * 32 + qh * 16 + quad * 4 + r) << 9) + n0 + s * 16 + col] +=
            eacc[s][r];
  } else {
    float be = b_end[0];
#pragma unroll
    for (int s = 0; s < 4; ++s)
#pragma unroll
      for (int r = 0; r < 4; ++r)
        eacc[s][r] += accb[((size_t)(b * 32 + qh * 16 + quad * 4 + r) << 9) +
                           n0 + s * 16 + col] + be;
    // final row softmax -> out
#pragma unroll
    for (int r = 0; r < 4; ++r) {
      float m = fmaxf(fmaxf(eacc[0][r], eacc[1][r]), fmaxf(eacc[2][r], eacc[3][r]));
#pragma unroll
      for (int o = 1; o < 16; o <<= 1) m = fmaxf(m, __shfl_xor(m, o, 64));
      red[r] = m;
    }
    if (col == 0)
#pragma unroll
      for (int r = 0; r < 4; ++r) s_red[(quad * 4 + r) * 8 + wave] = red[r];
    __syncthreads();
#pragma unroll
    for (int r = 0; r < 4; ++r) {
      float m = s_red[(quad * 4 + r) * 8];
#pragma unroll
      for (int w2 = 1; w2 < 8; ++w2) m = fmaxf(m, s_red[(quad * 4 + r) * 8 + w2]);
      M[r] = m;
    }
    __syncthreads();
#pragma unroll
    for (int s = 0; s < 4; ++s)
#pragma unroll
      for (int r = 0; r < 4; ++r) eacc[s][r] = fexp(eacc[s][r] - M[r]);
#pragma unroll
    for (int r = 0; r < 4; ++r) {
      float m = eacc[0][r] + eacc[1][r] + eacc[2][r] + eacc[3][r];
#pragma unroll
      for (int o = 1; o < 16; o <<= 1) m += __shfl_xor(m, o, 64);
      red[r] = m;
    }
    if (col == 0)
#pragma unroll
      for (int r = 0; r < 4; ++r) s_red[(quad * 4 + r) * 8 + wave] = red[r];
    __syncthreads();
#pragma unroll
    for (int r = 0; r < 4; ++r) {
      float m = s_red[(quad * 4 + r) * 8];
#pragma unroll
      for (int w2 = 1; w2 < 8; ++w2) m += s_red[(quad * 4 + r) * 8 + w2];
      M[r] = frcp(m);
    }
#pragma unroll
    for (int s = 0; s < 4; ++s)
#pragma unroll
      for (int r = 0; r < 4; ++r)
        out[((size_t)(b * 32 + qh * 16 + quad * 4 + r) << 9) + n0 + s * 16 + col] =
            eacc[s][r] * M[r];
  }
}

// ---------------------------------------------------------------------------
// Host orchestration (1 memset + 21 kernels)
// ---------------------------------------------------------------------------
extern "C" void kernel_launch(void* const* d_in, const int* in_sizes, int n_in,
                              void* d_out, int out_size, void* d_ws, size_t ws_size,
                              hipStream_t stream) {
  (void)in_sizes; (void)n_in; (void)out_size; (void)ws_size;
  const float* x_d = (const float*)d_in[0];
  const float* x_q = (const float*)d_in[1];
  const int* ei_d = (const int*)d_in[2];
  const int* ei_q = (const int*)d_in[3];
  const float* W1 = (const float*)d_in[6];
  const float* b1 = (const float*)d_in[7];
  const float* W2 = (const float*)d_in[8];
  const float* b2 = (const float*)d_in[9];
  const float* W3 = (const float*)d_in[10];
  const float* b3 = (const float*)d_in[11];
  const float* Wn[3] = {(const float*)d_in[12], (const float*)d_in[17], (const float*)d_in[22]};
  const float* Vn[3] = {(const float*)d_in[13], (const float*)d_in[18], (const float*)d_in[23]};
  const float* bn[3] = {(const float*)d_in[14], (const float*)d_in[19], (const float*)d_in[24]};
  const float* cw[3] = {(const float*)d_in[15], (const float*)d_in[20], (const float*)d_in[25]};
  const float* w_end = (const float*)d_in[27];
  const float* b_end = (const float*)d_in[28];
  float* out = (float*)d_out;

  char* wsp = (char*)d_ws;
  auto alloc = [&](size_t nbytes) {
    void* p = (void*)wsp;
    wsp += (nbytes + 255) & ~(size_t)255;
    return p;
  };
  int* cnt_d = (int*)alloc(cNd * 4);
  int* cnt_q = (int*)alloc(cNq * 4);
  int* cur_d = (int*)alloc(cNd * 4);
  int* cur_q = (int*)alloc(cNq * 4);
  float* dinv_d = (float*)alloc(cNd * 4);
  float* dinv_q = (float*)alloc(cNq * 4);
  int* rp_d = (int*)alloc(cNd * 4);
  int* rp_q = (int*)alloc(cNq * 4);
  int* col_d = (int*)alloc((size_t)cEd * 4);
  int* col_q = (int*)alloc((size_t)cEq * 4);
  int* bsum = (int*)alloc(64 * 4);
  ushort* xdbf = (ushort*)alloc((size_t)cNd * 64 * 2);
  ushort* xqbf = (ushort*)alloc((size_t)cNq * 64 * 2);
  ushort* w1T = (ushort*)alloc(128 * 64 * 2);
  ushort* w2T = (ushort*)alloc(128 * 128 * 2);
  ushort* w3T = (ushort*)alloc(128 * 128 * 2);
  ushort* wnT[3];
  for (int l = 0; l < 3; ++l) wnT[l] = (ushort*)alloc((size_t)16 * 128 * 128 * 2);
  ushort* vnbf[3];
  for (int l = 0; l < 3; ++l) vnbf[l] = (ushort*)alloc(16 * 256 * 2);
  ushort* htmp = (ushort*)alloc((size_t)(cNd + cNq) * 128 * 2);
  ushort* dbf = (ushort*)alloc((size_t)cNd * 128 * 2);
  ushort* qbf[3];
  for (int l = 0; l < 3; ++l) qbf[l] = (ushort*)alloc((size_t)cNq * 128 * 2);
  float* accb = (float*)alloc((size_t)cB * cNQ * cND * 4);
  ushort* qwbuf = (ushort*)alloc((size_t)cB * 16 * 32 * 128 * 2);

  const int* src_d = ei_d;
  const int* dst_d = ei_d + cEd;
  const int* src_q = ei_q;
  const int* dst_q = ei_q + cEq;

  hipMemsetAsync(cnt_d, 0, (size_t)2 * (cNd + cNq) * 4, stream);

  // --- conversions ---
  gmn_cvt_all<<<2188, 256, 0, stream>>>(x_d, x_q, Vn[0], Vn[1], Vn[2], xdbf, xqbf,
                                        vnbf[0], vnbf[1], vnbf[2]);
  gmn_t2bf_all<<<808, 256, 0, stream>>>(W1, W2, W3, Wn[0], Wn[1], Wn[2], w1T, w2T, w3T,
                                        wnT[0], wnT[1], wnT[2]);

  // --- CSR ---
  gmn_count_both<<<(cEd + cEq) / 256, 256, 0, stream>>>(dst_d, dst_q, cnt_d, cnt_q);
  gmn_scan_local_both<<<34, 1024, 0, stream>>>(cnt_d, cnt_q, rp_d, rp_q, bsum);
  gmn_scan_off_both<<<1, 64, 0, stream>>>(bsum);
  gmn_scan_add_both<<<34, 1024, 0, stream>>>(rp_d, rp_q, bsum);
  gmn_dinv_both<<<(cNd + cNq) / 256, 256, 0, stream>>>(cnt_d, cnt_q, dinv_d, dinv_q);
  gmn_fill_both<<<(cEd + cEq) / 256, 256, 0, stream>>>(src_d, dst_d, src_q, dst_q, rp_d,
                                                       rp_q, cur_d, cur_q, col_d, col_q);

  const ushort* wT[3] = {w1T, w2T, w3T};
  const float* bias[3] = {b1, b2, b3};
  const int o1s[3] = {0, 19, 3};
  const int o2s[3] = {-1, -1, 35};
  const int hasF[3] = {0, 1, 1};
  const int dosms[3] = {1, 0, 1};
  const int modes[3] = {0, 1, 2};

  for (int l = 0; l < 3; ++l) {
    if (l == 0)
      gmn_gemm_merged<64><<<(cNd + cNq) / 64, 256, 0, stream>>>(xdbf, xqbf, w1T, dinv_d,
                                                                dinv_q, htmp);
    else
      gmn_gemm_merged<128><<<(cNd + cNq) / 64, 256, 0, stream>>>(dbf, qbf[l - 1], wT[l],
                                                                 dinv_d, dinv_q, htmp);
    gmn_gather_merged<<<(cNd + cNq) / 8, 256, 0, stream>>>(htmp, rp_d, cnt_d, col_d,
                                                           dinv_d, rp_q, cnt_q, col_q,
                                                           dinv_q, bias[l], dbf, qbf[l]);
    gmn_qw<<<1024, 256, 0, stream>>>(qbf[l], wnT[l], qwbuf);
    gmn_level_fused<<<128, 512, 0, stream>>>(qbf[l], dbf, qwbuf, vnbf[l], bn[l], cw[l],
                                             w_end, b_end, o1s[l], o2s[l], hasF[l],
                                             dosms[l], modes[l], l, accb, out);
  }
}

// Round 9
// 300.573 us; speedup vs baseline: 1.4745x; 1.1783x over previous
//
#include <hip/hip_runtime.h>
#include <math.h>

// ---------------------------------------------------------------------------
// Problem constants (fixed production sizes from the reference)
// ---------------------------------------------------------------------------
namespace {
constexpr int cB  = 64;
constexpr int cNQ = 32;
constexpr int cND = 512;
constexpr int cNd = cB * cND;   // 32768
constexpr int cNq = cB * cNQ;   // 2048
constexpr int cEd = cNd * 8;    // 262144 (exactly 4096 per graph)
constexpr int cEq = cNq * 8;    // 16384  (exactly 256 per graph)
constexpr int LD_STRIDE = 516;
// front mega-kernel ranges
constexpr int NB_CVT = 2188, NB_T2BF = 808, NB_CNT = (cEd + cEq) / 256;
constexpr int NB_FILL = (cEd + cEq) / 256;  // 1088
}

#define F4C(p) (*(const float4*)(p))
#define F4W(p) (*(float4*)(p))

typedef __attribute__((ext_vector_type(8))) __bf16 bf16x8;
typedef __attribute__((ext_vector_type(4))) float floatx4;

__device__ __forceinline__ ushort f2bf(float f) {
  union { float f; unsigned u; } v;
  v.f = f;
  unsigned u = v.u;
  return (ushort)((u + 0x7fffu + ((u >> 16) & 1u)) >> 16);
}
__device__ __forceinline__ float bf2f(ushort u) {
  union { unsigned u; float f; } v;
  v.u = ((unsigned)u) << 16;
  return v.f;
}
__device__ __forceinline__ float4 us4f4(ushort4 u) {
  return make_float4(bf2f(u.x), bf2f(u.y), bf2f(u.z), bf2f(u.w));
}
__device__ __forceinline__ ushort4 f4us4(float4 f) {
  ushort4 o;
  o.x = f2bf(f.x); o.y = f2bf(f.y); o.z = f2bf(f.z); o.w = f2bf(f.w);
  return o;
}
__device__ __forceinline__ float fexp2(float x) {
#if __has_builtin(__builtin_amdgcn_exp2f)
  return __builtin_amdgcn_exp2f(x);
#else
  return exp2f(x);
#endif
}
__device__ __forceinline__ float frcp(float x) {
#if __has_builtin(__builtin_amdgcn_rcpf)
  return __builtin_amdgcn_rcpf(x);
#else
  return 1.0f / x;
#endif
}
__device__ __forceinline__ float fsigmoid(float z) {
  return frcp(1.0f + fexp2(z * -1.4426950408889634f));
}
__device__ __forceinline__ float fexp(float x) { return fexp2(x * 1.4426950408889634f); }

// XCD-affinity swizzle (blockIdx%8 -> XCD round-robin heuristic); low 6 bits only
__device__ __forceinline__ int swz_g(int j) { return (((j >> 3) & 7) << 3) | (j & 7); }

// ---------------------------------------------------------------------------
// D1 front: conversions + weight transposes + edge counts. grid 4084 x 256.
// ---------------------------------------------------------------------------
__global__ __launch_bounds__(256) void k_front(
    const float* __restrict__ xd, const float* __restrict__ xq,
    const float* __restrict__ v0, const float* __restrict__ v1,
    const float* __restrict__ v2, ushort* __restrict__ oxd, ushort* __restrict__ oxq,
    ushort* __restrict__ ov0, ushort* __restrict__ ov1, ushort* __restrict__ ov2,
    const float* __restrict__ W1, const float* __restrict__ W2,
    const float* __restrict__ W3, const float* __restrict__ Wn0,
    const float* __restrict__ Wn1, const float* __restrict__ Wn2,
    ushort* __restrict__ o1, ushort* __restrict__ o2, ushort* __restrict__ o3,
    ushort* __restrict__ on0, ushort* __restrict__ on1, ushort* __restrict__ on2,
    const int* __restrict__ dst_d, const int* __restrict__ dst_q,
    int* __restrict__ cnt_d, int* __restrict__ cnt_q) {
  __shared__ float tile[32][33];
  int blk = blockIdx.x, tid = threadIdx.x;
  if (blk < NB_CVT) {
    const float* src;
    ushort* dst;
    int i;
    if (blk < 2048) { src = xd; dst = oxd; i = blk * 256 + tid; }
    else if (blk < 2176) { src = xq; dst = oxq; i = (blk - 2048) * 256 + tid; }
    else if (blk < 2180) { src = v0; dst = ov0; i = (blk - 2176) * 256 + tid; }
    else if (blk < 2184) { src = v1; dst = ov1; i = (blk - 2180) * 256 + tid; }
    else { src = v2; dst = ov2; i = (blk - 2184) * 256 + tid; }
    *(ushort4*)(dst + (size_t)i * 4) = f4us4(F4C(src + (size_t)i * 4));
  } else if (blk < NB_CVT + NB_T2BF) {
    int b5 = blk - NB_CVT;
    const float* in;
    ushort* out;
    int R, C, bt, t;
    if (b5 < 8)        { in = W1;  out = o1;  R = 64;  C = 128; bt = 0; t = b5; }
    else if (b5 < 24)  { in = W2;  out = o2;  R = 128; C = 128; bt = 0; t = b5 - 8; }
    else if (b5 < 40)  { in = W3;  out = o3;  R = 128; C = 128; bt = 0; t = b5 - 24; }
    else if (b5 < 296) { in = Wn0; out = on0; R = 128; C = 128; bt = (b5 - 40) >> 4;  t = (b5 - 40) & 15; }
    else if (b5 < 552) { in = Wn1; out = on1; R = 128; C = 128; bt = (b5 - 296) >> 4; t = (b5 - 296) & 15; }
    else               { in = Wn2; out = on2; R = 128; C = 128; bt = (b5 - 552) >> 4; t = (b5 - 552) & 15; }
    int tilesC = C >> 5;
    int tr = t / tilesC, tc = t - tr * tilesC;
    int tx = tid & 31, ty = tid >> 5;
    const float* ib = in + (size_t)bt * R * C;
    ushort* ob = out + (size_t)bt * R * C;
#pragma unroll
    for (int i = 0; i < 4; ++i)
      tile[ty + i * 8][tx] = ib[(tr * 32 + ty + i * 8) * C + tc * 32 + tx];
    __syncthreads();
#pragma unroll
    for (int i = 0; i < 4; ++i)
      ob[(size_t)(tc * 32 + ty + i * 8) * R + tr * 32 + tx] = f2bf(tile[tx][ty + i * 8]);
  } else {
    int i = (blk - NB_CVT - NB_T2BF) * 256 + tid;
    if (i < cEd) atomicAdd(&cnt_d[dst_d[i]], 1);
    else atomicAdd(&cnt_q[dst_q[i - cEd]], 1);
  }
}

// ---------------------------------------------------------------------------
// D2: per-graph local scans (no cross-block propagation!) + dinv.
// grid 136 x 512: [0,64) data graph scans | [64,68) query (shfl-32 segmented)
// | [68,136) dinv. Exploits: graph g owns exactly 4096 data / 256 query edges.
// ---------------------------------------------------------------------------
__global__ __launch_bounds__(512) void k_scan_dinv(
    const int* __restrict__ cnt_d, const int* __restrict__ cnt_q,
    int* __restrict__ rp_d, int* __restrict__ rp_q,
    float* __restrict__ dinv_d, float* __restrict__ dinv_q) {
  __shared__ int sh[512];
  int blk = blockIdx.x, tid = threadIdx.x;
  if (blk < 64) {  // one data graph per block
    int v = cnt_d[blk * 512 + tid];
    sh[tid] = v;
    __syncthreads();
    for (int off = 1; off < 512; off <<= 1) {
      int t = (tid >= off) ? sh[tid - off] : 0;
      __syncthreads();
      sh[tid] += t;
      __syncthreads();
    }
    rp_d[blk * 512 + tid] = blk * 4096 + sh[tid] - v;  // exclusive + graph base
  } else if (blk < 68) {  // 16 query graphs per block (32 nodes each)
    int g = (blk - 64) * 16 + (tid >> 5);
    int lane32 = tid & 31;
    int v = cnt_q[g * 32 + lane32];
    int incl = v;
#pragma unroll
    for (int off = 1; off < 32; off <<= 1) {
      int t = __shfl_up(incl, off, 32);
      if (lane32 >= off) incl += t;
    }
    rp_q[g * 32 + lane32] = g * 256 + incl - v;
  } else {
    int i = (blk - 68) * 512 + tid;
    if (i < cNd) dinv_d[i] = 1.0f / sqrtf((float)(cnt_d[i] + 1));
    else dinv_q[i - cNd] = 1.0f / sqrtf((float)(cnt_q[i - cNd] + 1));
  }
}

// ---------------------------------------------------------------------------
// D3: CSR fill + GCN GEMM layer 1 (KD=64). grid 1632 x 256.
// ---------------------------------------------------------------------------
__global__ __launch_bounds__(256) void k_fill_gemm1(
    const int* __restrict__ src_d, const int* __restrict__ dst_d,
    const int* __restrict__ src_q, const int* __restrict__ dst_q,
    const int* __restrict__ rp_d, const int* __restrict__ rp_q,
    int* __restrict__ cur_d, int* __restrict__ cur_q, int* __restrict__ col_d,
    int* __restrict__ col_q, const ushort* __restrict__ xdbf,
    const ushort* __restrict__ xqbf, const ushort* __restrict__ w1T,
    const float* __restrict__ dinv_d, const float* __restrict__ dinv_q,
    ushort* __restrict__ htmp) {
  int blk = blockIdx.x, tid = threadIdx.x;
  if (blk < NB_FILL) {
    int i = blk * 256 + tid;
    if (i < cEd) {
      int d = dst_d[i];
      int p = atomicAdd(&cur_d[d], 1);
      col_d[rp_d[d] + p] = src_d[i];
    } else {
      int j = i - cEd;
      int d = dst_q[j];
      int p = atomicAdd(&cur_q[d], 1);
      col_q[rp_q[d] + p] = src_q[j];
    }
    return;
  }
  int blk2 = blk - NB_FILL;  // [0,544): data [0,512) swizzled, query [512,544)
  int wave = tid >> 6, lane = tid & 63;
  int col = lane & 15, quad = lane >> 4;
  bool isQ = blk2 >= 512;
  int node0;
  if (isQ) node0 = (blk2 - 512) * 64;
  else node0 = swz_g(blk2) * 512 + (blk2 >> 6) * 64;
  int mloc = node0 + wave * 16;
  const ushort* X = isQ ? xqbf : xdbf;
  const float* dv = isQ ? dinv_q : dinv_d;
  size_t hbase = isQ ? (size_t)cNd : 0;
  floatx4 acc[8];
#pragma unroll
  for (int ct = 0; ct < 8; ++ct)
#pragma unroll
    for (int r = 0; r < 4; ++r) acc[ct][r] = 0.0f;
#pragma unroll
  for (int kc = 0; kc < 2; ++kc) {
    bf16x8 a = *(const bf16x8*)(X + (size_t)(mloc + col) * 64 + kc * 32 + quad * 8);
#pragma unroll
    for (int ct = 0; ct < 8; ++ct) {
      bf16x8 b = *(const bf16x8*)(w1T + (size_t)(ct * 16 + col) * 64 + kc * 32 + quad * 8);
      acc[ct] = __builtin_amdgcn_mfma_f32_16x16x32_bf16(a, b, acc[ct], 0, 0, 0);
    }
  }
  float sc[4];
#pragma unroll
  for (int r = 0; r < 4; ++r) sc[r] = dv[mloc + quad * 4 + r];
#pragma unroll
  for (int ct = 0; ct < 8; ++ct)
#pragma unroll
    for (int r = 0; r < 4; ++r)
      htmp[(hbase + mloc + quad * 4 + r) * 128 + ct * 16 + col] = f2bf(acc[ct][r] * sc[r]);
}

// ---------------------------------------------------------------------------
// GCN aggregate (XCD-swizzled, predicated neighbor loads). grid 4352 x 256.
// ---------------------------------------------------------------------------
__global__ __launch_bounds__(256) void gmn_gather_merged(
    const ushort* __restrict__ htmp, const int* __restrict__ rp_d,
    const int* __restrict__ cnt_d, const int* __restrict__ col_d,
    const float* __restrict__ dinv_d, const int* __restrict__ rp_q,
    const int* __restrict__ cnt_q, const int* __restrict__ col_q,
    const float* __restrict__ dinv_q, const float* __restrict__ bias,
    ushort* __restrict__ dbf, ushort* __restrict__ qbf) {
  int blk = blockIdx.x, tid = threadIdx.x;
  bool isQ = blk >= 4096;
  int node;
  if (isQ) {
    int j = blk - 4096;
    node = swz_g(j) * 32 + (j >> 6) * 8 + (tid >> 5);
  } else {
    node = swz_g(blk) * 512 + (blk >> 6) * 8 + (tid >> 5);
  }
  int l = tid & 31;
  const ushort* hs = htmp + (isQ ? (size_t)cNd * 128 : 0);
  const int* rp = isQ ? rp_q : rp_d;
  const int* cnt = isQ ? cnt_q : cnt_d;
  const int* col = isQ ? col_q : col_d;
  const float* dinv = isQ ? dinv_q : dinv_d;
  ushort* outp = isQ ? qbf : dbf;
  int c = cnt[node], s0 = rp[node];
  float dt = dinv[node];
  float4 acc = us4f4(*(const ushort4*)(hs + (size_t)node * 128 + l * 4));
  int cm = c < 32 ? c : 32;
  for (int j0 = 0; j0 < cm; j0 += 8) {
    int ss[8];
    ushort4 v[8];
#pragma unroll
    for (int t = 0; t < 8; ++t) {
      int jj = j0 + t;
      ss[t] = (jj < cm) ? col[s0 + jj] : -1;
    }
#pragma unroll
    for (int t = 0; t < 8; ++t)
      if (ss[t] >= 0) v[t] = *(const ushort4*)(hs + (size_t)ss[t] * 128 + l * 4);
#pragma unroll
    for (int t = 0; t < 8; ++t) {
      if (ss[t] >= 0) {
        float4 f = us4f4(v[t]);
        acc.x += f.x; acc.y += f.y; acc.z += f.z; acc.w += f.w;
      }
    }
  }
  for (int j = 32; j < c; ++j) {
    int s = col[s0 + j];
    float4 f = us4f4(*(const ushort4*)(hs + (size_t)s * 128 + l * 4));
    acc.x += f.x; acc.y += f.y; acc.z += f.z; acc.w += f.w;
  }
  float4 bv = F4C(bias + l * 4);
  float4 r;
  r.x = fmaxf(acc.x * dt + bv.x, 0.0f);
  r.y = fmaxf(acc.y * dt + bv.y, 0.0f);
  r.z = fmaxf(acc.z * dt + bv.z, 0.0f);
  r.w = fmaxf(acc.w * dt + bv.w, 0.0f);
  *(ushort4*)(outp + (size_t)node * 128 + l * 4) = f4us4(r);
}

// ---------------------------------------------------------------------------
// qW prep (XCD-swizzled): qW[b,k] = q[b] @ Wn[k]. grid 1024 x 256.
// ---------------------------------------------------------------------------
__global__ __launch_bounds__(256) void gmn_qw(const ushort* __restrict__ qbf,
                                              const ushort* __restrict__ wnT,
                                              ushort* __restrict__ qw) {
  int blk = blockIdx.x, tid = threadIdx.x;
  int wave = tid >> 6, lane = tid & 63;
  int col = lane & 15, quad = lane >> 4;
  int b = swz_g(blk), k = blk >> 6;
  int et0 = wave * 2;
  floatx4 acc[2][2];
#pragma unroll
  for (int qt = 0; qt < 2; ++qt)
#pragma unroll
    for (int ei = 0; ei < 2; ++ei)
#pragma unroll
      for (int r = 0; r < 4; ++r) acc[qt][ei][r] = 0.0f;
#pragma unroll
  for (int kc = 0; kc < 4; ++kc) {
    bf16x8 a0 = *(const bf16x8*)(qbf + (size_t)(b * 32 + col) * 128 + kc * 32 + quad * 8);
    bf16x8 a1 = *(const bf16x8*)(qbf + (size_t)(b * 32 + 16 + col) * 128 + kc * 32 + quad * 8);
#pragma unroll
    for (int ei = 0; ei < 2; ++ei) {
      bf16x8 bf = *(const bf16x8*)(wnT + (size_t)(k * 128 + (et0 + ei) * 16 + col) * 128 +
                                   kc * 32 + quad * 8);
      acc[0][ei] = __builtin_amdgcn_mfma_f32_16x16x32_bf16(a0, bf, acc[0][ei], 0, 0, 0);
      acc[1][ei] = __builtin_amdgcn_mfma_f32_16x16x32_bf16(a1, bf, acc[1][ei], 0, 0, 0);
    }
  }
#pragma unroll
  for (int qt = 0; qt < 2; ++qt)
#pragma unroll
    for (int ei = 0; ei < 2; ++ei)
#pragma unroll
      for (int r = 0; r < 4; ++r)
        qw[((size_t)(b * 16 + k) << 12) + (qt * 16 + quad * 4 + r) * 128 +
           (et0 + ei) * 16 + col] = f2bf(acc[qt][ei][r]);
}

// ---------------------------------------------------------------------------
// Merged dispatch: row-complete fused NTN level [blk<128, 512 thr]  +
// next-layer GCN GEMM KD=128 [blk in [128,128+nb_gemm), 8 waves x 16 rows].
// Both depend only on the PREVIOUS dispatch (gather/qw outputs) — independent.
// ---------------------------------------------------------------------------
__global__ __launch_bounds__(512, 2) void k_level_gemm(
    const ushort* __restrict__ qbf, const ushort* __restrict__ dbf,
    const ushort* __restrict__ qw, const ushort* __restrict__ vnbf,
    const float* __restrict__ bn, const float* __restrict__ cw,
    const float* __restrict__ w_end, const float* __restrict__ b_end,
    int o1, int o2, int hasF, int do_sm, int mode, int widx,
    float* __restrict__ accb, float* __restrict__ out,
    const ushort* __restrict__ gWT, const float* __restrict__ dinv_d,
    const float* __restrict__ dinv_q, ushort* __restrict__ htmp) {
  __shared__ float s_ld[16 * LD_STRIDE];
  __shared__ float s_lq[16 * 16];
  __shared__ float s_red[16 * 8];
  int tid = threadIdx.x;
  int wave = tid >> 6, lane = tid & 63;
  int col = lane & 15, quad = lane >> 4;

  if (blockIdx.x >= 128) {  // ---------------- GEMM KD=128 section ----------
    int gblk = blockIdx.x - 128;  // [0,272): data [0,256), query [256,272)
    bool isQ = gblk >= 256;
    int node0;
    if (isQ) node0 = (gblk - 256) * 128;
    else node0 = swz_g(gblk) * 512 + (gblk >> 6) * 128;
    int mloc = node0 + wave * 16;
    const ushort* X = isQ ? qbf : dbf;
    const float* dv = isQ ? dinv_q : dinv_d;
    size_t hbase = isQ ? (size_t)cNd : 0;
    floatx4 acc[8];
#pragma unroll
    for (int ct = 0; ct < 8; ++ct)
#pragma unroll
      for (int r = 0; r < 4; ++r) acc[ct][r] = 0.0f;
#pragma unroll
    for (int kc = 0; kc < 4; ++kc) {
      bf16x8 a = *(const bf16x8*)(X + (size_t)(mloc + col) * 128 + kc * 32 + quad * 8);
#pragma unroll
      for (int ct = 0; ct < 8; ++ct) {
        bf16x8 b = *(const bf16x8*)(gWT + (size_t)(ct * 16 + col) * 128 + kc * 32 + quad * 8);
        acc[ct] = __builtin_amdgcn_mfma_f32_16x16x32_bf16(a, b, acc[ct], 0, 0, 0);
      }
    }
    float sc[4];
#pragma unroll
    for (int r = 0; r < 4; ++r) sc[r] = dv[mloc + quad * 4 + r];
#pragma unroll
    for (int ct = 0; ct < 8; ++ct)
#pragma unroll
      for (int r = 0; r < 4; ++r)
        htmp[(hbase + mloc + quad * 4 + r) * 128 + ct * 16 + col] = f2bf(acc[ct][r] * sc[r]);
    return;
  }

  // ---------------- fused level section (identical numerics to R8) --------
  int b = swz_g(blockIdx.x & 63);
  int qh = blockIdx.x >> 6;
  int n0 = wave * 64;

  bf16x8 bfr[4][4];
#pragma unroll
  for (int s = 0; s < 4; ++s)
#pragma unroll
    for (int kc = 0; kc < 4; ++kc)
      bfr[s][kc] = *(const bf16x8*)(dbf + ((size_t)(b * 512 + n0 + s * 16 + col) << 7) +
                                    kc * 32 + quad * 8);
  bf16x8 aq[4];
#pragma unroll
  for (int kc = 0; kc < 4; ++kc)
    aq[kc] = *(const bf16x8*)(qbf + (size_t)(b * 32 + qh * 16 + col) * 128 +
                              kc * 32 + quad * 8);

  floatx4 att[4];
#pragma unroll
  for (int s = 0; s < 4; ++s)
#pragma unroll
    for (int r = 0; r < 4; ++r) att[s][r] = 0.0f;
#pragma unroll
  for (int kc = 0; kc < 4; ++kc)
#pragma unroll
    for (int s = 0; s < 4; ++s)
      att[s] = __builtin_amdgcn_mfma_f32_16x16x32_bf16(aq[kc], bfr[s][kc], att[s], 0, 0, 0);
  const float sc = 0.088388347648318440550f;
#pragma unroll
  for (int s = 0; s < 4; ++s)
#pragma unroll
    for (int r = 0; r < 4; ++r) att[s][r] *= sc;

  {
    bf16x8 vn2[4];
#pragma unroll
    for (int kc = 0; kc < 4; ++kc)
      vn2[kc] = *(const bf16x8*)(vnbf + col * 256 + 128 + kc * 32 + quad * 8);
#pragma unroll
    for (int s = 0; s < 4; ++s) {
      floatx4 lda;
#pragma unroll
      for (int r = 0; r < 4; ++r) lda[r] = 0.0f;
#pragma unroll
      for (int kc = 0; kc < 4; ++kc)
        lda = __builtin_amdgcn_mfma_f32_16x16x32_bf16(bfr[s][kc], vn2[kc], lda, 0, 0, 0);
#pragma unroll
      for (int r = 0; r < 4; ++r)
        s_ld[col * LD_STRIDE + n0 + s * 16 + quad * 4 + r] = lda[r];
    }
  }
  if (wave == 0) {
    bf16x8 vn1[4];
#pragma unroll
    for (int kc = 0; kc < 4; ++kc)
      vn1[kc] = *(const bf16x8*)(vnbf + col * 256 + kc * 32 + quad * 8);
    floatx4 lqa;
#pragma unroll
    for (int r = 0; r < 4; ++r) lqa[r] = 0.0f;
#pragma unroll
    for (int kc = 0; kc < 4; ++kc)
      lqa = __builtin_amdgcn_mfma_f32_16x16x32_bf16(aq[kc], vn1[kc], lqa, 0, 0, 0);
#pragma unroll
    for (int r = 0; r < 4; ++r) s_lq[col * 16 + quad * 4 + r] = lqa[r];
  }
  __syncthreads();

  float red[4], M[4];
#pragma unroll
  for (int r = 0; r < 4; ++r) {
    float m = fmaxf(fmaxf(att[0][r], att[1][r]), fmaxf(att[2][r], att[3][r]));
#pragma unroll
    for (int o = 1; o < 16; o <<= 1) m = fmaxf(m, __shfl_xor(m, o, 64));
    red[r] = m;
  }
  if (col == 0)
#pragma unroll
    for (int r = 0; r < 4; ++r) s_red[(quad * 4 + r) * 8 + wave] = red[r];
  __syncthreads();
#pragma unroll
  for (int r = 0; r < 4; ++r) {
    float m = s_red[(quad * 4 + r) * 8];
#pragma unroll
    for (int w = 1; w < 8; ++w) m = fmaxf(m, s_red[(quad * 4 + r) * 8 + w]);
    M[r] = m;
  }
  __syncthreads();
#pragma unroll
  for (int s = 0; s < 4; ++s)
#pragma unroll
    for (int r = 0; r < 4; ++r) att[s][r] = fexp(att[s][r] - M[r]);
#pragma unroll
  for (int r = 0; r < 4; ++r) {
    float m = att[0][r] + att[1][r] + att[2][r] + att[3][r];
#pragma unroll
    for (int o = 1; o < 16; o <<= 1) m += __shfl_xor(m, o, 64);
    red[r] = m;
  }
  if (col == 0)
#pragma unroll
    for (int r = 0; r < 4; ++r) s_red[(quad * 4 + r) * 8 + wave] = red[r];
  __syncthreads();
#pragma unroll
  for (int r = 0; r < 4; ++r) {
    float m = s_red[(quad * 4 + r) * 8];
#pragma unroll
    for (int w = 1; w < 8; ++w) m += s_red[(quad * 4 + r) * 8 + w];
    M[r] = frcp(m);
  }
  __syncthreads();
#pragma unroll
  for (int s = 0; s < 4; ++s)
#pragma unroll
    for (int r = 0; r < 4; ++r) att[s][r] *= M[r];

  floatx4 eacc[4], facc[4];
#pragma unroll
  for (int s = 0; s < 4; ++s)
#pragma unroll
    for (int r = 0; r < 4; ++r) { eacc[s][r] = 0.0f; facc[s][r] = 0.0f; }

#pragma unroll 4
  for (int k = 0; k < 16; ++k) {
    const ushort* qk = qw + ((size_t)(b * 16 + k) << 12) + (qh * 16 + col) * 128 + quad * 8;
    bf16x8 a0 = *(const bf16x8*)(qk);
    bf16x8 a1 = *(const bf16x8*)(qk + 32);
    bf16x8 a2 = *(const bf16x8*)(qk + 64);
    bf16x8 a3 = *(const bf16x8*)(qk + 96);
    floatx4 bil[4];
#pragma unroll
    for (int s = 0; s < 4; ++s) {
#pragma unroll
      for (int r = 0; r < 4; ++r) bil[s][r] = 0.0f;
      bil[s] = __builtin_amdgcn_mfma_f32_16x16x32_bf16(a0, bfr[s][0], bil[s], 0, 0, 0);
      bil[s] = __builtin_amdgcn_mfma_f32_16x16x32_bf16(a1, bfr[s][1], bil[s], 0, 0, 0);
      bil[s] = __builtin_amdgcn_mfma_f32_16x16x32_bf16(a2, bfr[s][2], bil[s], 0, 0, 0);
      bil[s] = __builtin_amdgcn_mfma_f32_16x16x32_bf16(a3, bfr[s][3], bil[s], 0, 0, 0);
    }
    float bnk = bn[k], cwk = cw[k];
    float wkk = 0.0f;
    if (hasF) {
      wkk = w_end[o1 + k];
      if (o2 >= 0) wkk += w_end[o2 + k];
    }
    float lqv[4];
#pragma unroll
    for (int r = 0; r < 4; ++r) lqv[r] = s_lq[k * 16 + quad * 4 + r] + bnk;
#pragma unroll
    for (int s = 0; s < 4; ++s) {
      float ldv = s_ld[k * LD_STRIDE + n0 + s * 16 + col];
#pragma unroll
      for (int r = 0; r < 4; ++r) {
        float sg = fsigmoid(bil[s][r] + lqv[r] + ldv);
        eacc[s][r] += cwk * sg;
        facc[s][r] += wkk * sg;
      }
    }
  }

#pragma unroll
  for (int s = 0; s < 4; ++s)
#pragma unroll
    for (int r = 0; r < 4; ++r) {
      eacc[s][r] *= att[s][r];
      facc[s][r] *= att[s][r];
    }
  if (do_sm) {
#pragma unroll
    for (int r = 0; r < 4; ++r) {
      float m = fmaxf(fmaxf(eacc[0][r], eacc[1][r]), fmaxf(eacc[2][r], eacc[3][r]));
#pragma unroll
      for (int o = 1; o < 16; o <<= 1) m = fmaxf(m, __shfl_xor(m, o, 64));
      red[r] = m;
    }
    if (col == 0)
#pragma unroll
      for (int r = 0; r < 4; ++r) s_red[(quad * 4 + r) * 8 + wave] = red[r];
    __syncthreads();
#pragma unroll
    for (int r = 0; r < 4; ++r) {
      float m = s_red[(quad * 4 + r) * 8];
#pragma unroll
      for (int w = 1; w < 8; ++w) m = fmaxf(m, s_red[(quad * 4 + r) * 8 + w]);
      M[r] = m;
    }
    __syncthreads();
#pragma unroll
    for (int s = 0; s < 4; ++s)
#pragma unroll
      for (int r = 0; r < 4; ++r) eacc[s][r] = fexp(eacc[s][r] - M[r]);
#pragma unroll
    for (int r = 0; r < 4; ++r) {
      float m = eacc[0][r] + eacc[1][r] + eacc[2][r] + eacc[3][r];
#pragma unroll
      for (int o = 1; o < 16; o <<= 1) m += __shfl_xor(m, o, 64);
      red[r] = m;
    }
    if (col == 0)
#pragma unroll
      for (int r = 0; r < 4; ++r) s_red[(quad * 4 + r) * 8 + wave] = red[r];
    __syncthreads();
#pragma unroll
    for (int r = 0; r < 4; ++r) {
      float m = s_red[(quad * 4 + r) * 8];
#pragma unroll
      for (int w = 1; w < 8; ++w) m += s_red[(quad * 4 + r) * 8 + w];
      M[r] = frcp(m);
    }
    __syncthreads();
#pragma unroll
    for (int s = 0; s < 4; ++s)
#pragma unroll
      for (int r = 0; r < 4; ++r) eacc[s][r] *= M[r];
  }
  float w = w_end[widx];
#pragma unroll
  for (int s = 0; s < 4; ++s)
#pragma unroll
    for (int r = 0; r < 4; ++r) eacc[s][r] = w * eacc[s][r] + (hasF ? facc[s][r] : 0.0f);

  if (mode == 0) {
#pragma unroll
    for (int s = 0; s < 4; ++s)
#pragma unroll
      for (int r = 0; r < 4; ++r)
        accb[((size_t)(b * 32 + qh * 16 + quad * 4 + r) << 9) + n0 + s * 16 + col] =
            eacc[s][r];
  } else if (mode == 1) {
#pragma unroll
    for (int s = 0; s < 4; ++s)
#pragma unroll
      for (int r = 0; r < 4; ++r)
        accb[((size_t)(b * 32 + qh * 16 + quad * 4 + r) << 9) + n0 + s * 16 + col] +=
            eacc[s][r];
  } else {
    float be = b_end[0];
#pragma unroll
    for (int s = 0; s < 4; ++s)
#pragma unroll
      for (int r = 0; r < 4; ++r)
        eacc[s][r] += accb[((size_t)(b * 32 + qh * 16 + quad * 4 + r) << 9) +
                           n0 + s * 16 + col] + be;
#pragma unroll
    for (int r = 0; r < 4; ++r) {
      float m = fmaxf(fmaxf(eacc[0][r], eacc[1][r]), fmaxf(eacc[2][r], eacc[3][r]));
#pragma unroll
      for (int o = 1; o < 16; o <<= 1) m = fmaxf(m, __shfl_xor(m, o, 64));
      red[r] = m;
    }
    if (col == 0)
#pragma unroll
      for (int r = 0; r < 4; ++r) s_red[(quad * 4 + r) * 8 + wave] = red[r];
    __syncthreads();
#pragma unroll
    for (int r = 0; r < 4; ++r) {
      float m = s_red[(quad * 4 + r) * 8];
#pragma unroll
      for (int w2 = 1; w2 < 8; ++w2) m = fmaxf(m, s_red[(quad * 4 + r) * 8 + w2]);
      M[r] = m;
    }
    __syncthreads();
#pragma unroll
    for (int s = 0; s < 4; ++s)
#pragma unroll
      for (int r = 0; r < 4; ++r) eacc[s][r] = fexp(eacc[s][r] - M[r]);
#pragma unroll
    for (int r = 0; r < 4; ++r) {
      float m = eacc[0][r] + eacc[1][r] + eacc[2][r] + eacc[3][r];
#pragma unroll
      for (int o = 1; o < 16; o <<= 1) m += __shfl_xor(m, o, 64);
      red[r] = m;
    }
    if (col == 0)
#pragma unroll
      for (int r = 0; r < 4; ++r) s_red[(quad * 4 + r) * 8 + wave] = red[r];
    __syncthreads();
#pragma unroll
    for (int r = 0; r < 4; ++r) {
      float m = s_red[(quad * 4 + r) * 8];
#pragma unroll
      for (int w2 = 1; w2 < 8; ++w2) m += s_red[(quad * 4 + r) * 8 + w2];
      M[r] = frcp(m);
    }
#pragma unroll
    for (int s = 0; s < 4; ++s)
#pragma unroll
      for (int r = 0; r < 4; ++r)
        out[((size_t)(b * 32 + qh * 16 + quad * 4 + r) << 9) + n0 + s * 16 + col] =
            eacc[s][r] * M[r];
  }
}

// ---------------------------------------------------------------------------
// Host orchestration — 13 dispatches (1 memset + 12 kernels)
// ---------------------------------------------------------------------------
extern "C" void kernel_launch(void* const* d_in, const int* in_sizes, int n_in,
                              void* d_out, int out_size, void* d_ws, size_t ws_size,
                              hipStream_t stream) {
  (void)in_sizes; (void)n_in; (void)out_size; (void)ws_size;
  const float* x_d = (const float*)d_in[0];
  const float* x_q = (const float*)d_in[1];
  const int* ei_d = (const int*)d_in[2];
  const int* ei_q = (const int*)d_in[3];
  const float* W1 = (const float*)d_in[6];
  const float* b1 = (const float*)d_in[7];
  const float* W2 = (const float*)d_in[8];
  const float* b2 = (const float*)d_in[9];
  const float* W3 = (const float*)d_in[10];
  const float* b3 = (const float*)d_in[11];
  const float* Wn[3] = {(const float*)d_in[12], (const float*)d_in[17], (const float*)d_in[22]};
  const float* Vn[3] = {(const float*)d_in[13], (const float*)d_in[18], (const float*)d_in[23]};
  const float* bn[3] = {(const float*)d_in[14], (const float*)d_in[19], (const float*)d_in[24]};
  const float* cw[3] = {(const float*)d_in[15], (const float*)d_in[20], (const float*)d_in[25]};
  const float* w_end = (const float*)d_in[27];
  const float* b_end = (const float*)d_in[28];
  float* out = (float*)d_out;

  char* wsp = (char*)d_ws;
  auto alloc = [&](size_t nbytes) {
    void* p = (void*)wsp;
    wsp += (nbytes + 255) & ~(size_t)255;
    return p;
  };
  int* cnt_d = (int*)alloc(cNd * 4);
  int* cnt_q = (int*)alloc(cNq * 4);
  int* cur_d = (int*)alloc(cNd * 4);
  int* cur_q = (int*)alloc(cNq * 4);
  float* dinv_d = (float*)alloc(cNd * 4);
  float* dinv_q = (float*)alloc(cNq * 4);
  int* rp_d = (int*)alloc(cNd * 4);
  int* rp_q = (int*)alloc(cNq * 4);
  int* col_d = (int*)alloc((size_t)cEd * 4);
  int* col_q = (int*)alloc((size_t)cEq * 4);
  ushort* xdbf = (ushort*)alloc((size_t)cNd * 64 * 2);
  ushort* xqbf = (ushort*)alloc((size_t)cNq * 64 * 2);
  ushort* w1T = (ushort*)alloc(128 * 64 * 2);
  ushort* w2T = (ushort*)alloc(128 * 128 * 2);
  ushort* w3T = (ushort*)alloc(128 * 128 * 2);
  ushort* wnT[3];
  for (int l = 0; l < 3; ++l) wnT[l] = (ushort*)alloc((size_t)16 * 128 * 128 * 2);
  ushort* vnbf[3];
  for (int l = 0; l < 3; ++l) vnbf[l] = (ushort*)alloc(16 * 256 * 2);
  ushort* htmp = (ushort*)alloc((size_t)(cNd + cNq) * 128 * 2);
  ushort* dbf = (ushort*)alloc((size_t)cNd * 128 * 2);
  ushort* qbf[3];
  for (int l = 0; l < 3; ++l) qbf[l] = (ushort*)alloc((size_t)cNq * 128 * 2);
  float* accb = (float*)alloc((size_t)cB * cNQ * cND * 4);
  ushort* qwbuf = (ushort*)alloc((size_t)cB * 16 * 32 * 128 * 2);

  const int* src_d = ei_d;
  const int* dst_d = ei_d + cEd;
  const int* src_q = ei_q;
  const int* dst_q = ei_q + cEq;

  hipMemsetAsync(cnt_d, 0, (size_t)2 * (cNd + cNq) * 4, stream);

  // D1: conversions + transposes + edge counts
  k_front<<<NB_CVT + NB_T2BF + NB_CNT, 256, 0, stream>>>(
      x_d, x_q, Vn[0], Vn[1], Vn[2], xdbf, xqbf, vnbf[0], vnbf[1], vnbf[2], W1, W2,
      W3, Wn[0], Wn[1], Wn[2], w1T, w2T, w3T, wnT[0], wnT[1], wnT[2], dst_d, dst_q,
      cnt_d, cnt_q);

  // D2: per-graph local scans + dinv (no cross-block propagation)
  k_scan_dinv<<<136, 512, 0, stream>>>(cnt_d, cnt_q, rp_d, rp_q, dinv_d, dinv_q);

  // D3: CSR fill + GEMM layer 1
  k_fill_gemm1<<<NB_FILL + 544, 256, 0, stream>>>(
      src_d, dst_d, src_q, dst_q, rp_d, rp_q, cur_d, cur_q, col_d, col_q, xdbf, xqbf,
      w1T, dinv_d, dinv_q, htmp);

  const float* bias[3] = {b1, b2, b3};
  const ushort* nextWT[3] = {w2T, w3T, nullptr};
  const int o1s[3] = {0, 19, 3};
  const int o2s[3] = {-1, -1, 35};
  const int hasF[3] = {0, 1, 1};
  const int dosms[3] = {1, 0, 1};
  const int modes[3] = {0, 1, 2};

  for (int l = 0; l < 3; ++l) {
    // gather layer l -> dbf, qbf[l]
    gmn_gather_merged<<<(cNd + cNq) / 8, 256, 0, stream>>>(
        htmp, rp_d, cnt_d, col_d, dinv_d, rp_q, cnt_q, col_q, dinv_q, bias[l], dbf,
        qbf[l]);
    // qW for level l
    gmn_qw<<<1024, 256, 0, stream>>>(qbf[l], wnT[l], qwbuf);
    // fused level l  (+ GEMM for layer l+1, co-dispatched, independent)
    int grid = (l < 2) ? (128 + 272) : 128;
    k_level_gemm<<<grid, 512, 0, stream>>>(
        qbf[l], dbf, qwbuf, vnbf[l], bn[l], cw[l], w_end, b_end, o1s[l], o2s[l],
        hasF[l], dosms[l], modes[l], l, accb, out, nextWT[l], dinv_d, dinv_q, htmp);
  }
}